// Round 1
// baseline (4213.255 us; speedup 1.0000x reference)
//
#include <hip/hip_runtime.h>
#include <hip/hip_bf16.h>

#define NN 50000
#define EE 1200000
#define GG 256
#define LL 5

__device__ __forceinline__ float silu_f(float x) { return x / (1.0f + expf(-x)); }

// ---------- CSR build ----------
__global__ __launch_bounds__(256) void k_hist(const int* __restrict__ ei, int* __restrict__ fill, int E) {
    int e = blockIdx.x * 256 + threadIdx.x;
    if (e < E) atomicAdd(&fill[ei[E + e]], 1);
}

__global__ __launch_bounds__(1024) void k_scan(const int* __restrict__ cnt, int* __restrict__ rowptr,
                                               float* __restrict__ degf, int* __restrict__ fill, int n) {
    __shared__ int wsum[16];
    __shared__ int carry_s;
    int tid = threadIdx.x, lane = tid & 63, wid = tid >> 6;
    if (tid == 0) carry_s = 0;
    __syncthreads();
    for (int base = 0; base < n; base += 1024) {
        int i = base + tid;
        int v = (i < n) ? cnt[i] : 0;
        int x = v;
        #pragma unroll
        for (int off = 1; off < 64; off <<= 1) {
            int t = __shfl_up(x, off);
            if (lane >= off) x += t;
        }
        if (lane == 63) wsum[wid] = x;
        __syncthreads();
        if (wid == 0 && lane < 16) {
            int w = wsum[lane];
            #pragma unroll
            for (int off = 1; off < 16; off <<= 1) {
                int t = __shfl_up(w, off);
                if (lane >= off) w += t;
            }
            wsum[lane] = w;
        }
        __syncthreads();
        int waveoff = (wid == 0) ? 0 : wsum[wid - 1];
        int inc = x + waveoff;
        int c = carry_s;
        int chunk_total = wsum[15];
        __syncthreads();
        if (i < n) {
            rowptr[i + 1] = c + inc;
            degf[i] = (float)(v > 0 ? v : 1);
            fill[i] = 0;
        }
        if (tid == 0) {
            if (base == 0) rowptr[0] = 0;
            carry_s = c + chunk_total;
        }
        __syncthreads();
    }
}

__global__ __launch_bounds__(256) void k_scatter(const int* __restrict__ ei, const float* __restrict__ ea,
                                                 const int* __restrict__ rowptr, int* __restrict__ fill,
                                                 int* __restrict__ srcs, float* __restrict__ eas, int E) {
    int e = blockIdx.x * 256 + threadIdx.x;
    if (e < E) {
        int d = ei[E + e];
        int pos = atomicAdd(&fill[d], 1);
        int idx = rowptr[d] + pos;
        srcs[idx] = ei[e];
        eas[idx] = ea[e];
    }
}

// ---------- node embedding: h = x @ node_W + node_b  (x: [N,92]) ----------
__global__ __launch_bounds__(256) void k_node_emb(const float* __restrict__ x, const float* __restrict__ W,
                                                  const float* __restrict__ b, float* __restrict__ h, int n) {
    __shared__ float sW[92 * 64];
    for (int i = threadIdx.x; i < 92 * 64; i += 256) sW[i] = W[i];
    __syncthreads();
    int lane = threadIdx.x & 63;
    int gw = (blockIdx.x * 256 + threadIdx.x) >> 6;
    int nw = (gridDim.x * 256) >> 6;
    float bj = b[lane];
    for (int row = gw; row < n; row += nw) {
        const float* xr = x + (size_t)row * 92;
        float xa = xr[lane];
        float xb = (lane < 28) ? xr[64 + lane] : 0.0f;
        float acc = bj;
        #pragma unroll
        for (int k = 0; k < 64; k++) acc = fmaf(__shfl(xa, k), sW[k * 64 + lane], acc);
        #pragma unroll
        for (int k = 0; k < 28; k++) acc = fmaf(__shfl(xb, k), sW[(64 + k) * 64 + lane], acc);
        h[(size_t)row * 64 + lane] = acc;
    }
}

// ---------- per-layer: Hd = h@W1[0:64] + b1 ; Hs = h@W1[64:128] ----------
__global__ __launch_bounds__(256) void k_node_pre(const float* __restrict__ h, const float* __restrict__ W1,
                                                  const float* __restrict__ b1, float* __restrict__ Hd,
                                                  float* __restrict__ Hs, int n) {
    __shared__ float sA[4096], sB[4096];
    for (int i = threadIdx.x; i < 4096; i += 256) { sA[i] = W1[i]; sB[i] = W1[4096 + i]; }
    __syncthreads();
    int lane = threadIdx.x & 63;
    int gw = (blockIdx.x * 256 + threadIdx.x) >> 6;
    int nw = (gridDim.x * 256) >> 6;
    float bj = b1[lane];
    for (int row = gw; row < n; row += nw) {
        float hv = h[(size_t)row * 64 + lane];
        float a = bj, c = 0.0f;
        #pragma unroll
        for (int k = 0; k < 64; k++) {
            float hk = __shfl(hv, k);
            a = fmaf(hk, sA[k * 64 + lane], a);
            c = fmaf(hk, sB[k * 64 + lane], c);
        }
        Hd[(size_t)row * 64 + lane] = a;
        Hs[(size_t)row * 64 + lane] = c;
    }
}

// ---------- edge pass 1: accumulate sum(z), sum(z^2) per column ----------
__global__ __launch_bounds__(256) void k_edge_stats(const float* __restrict__ Hd, const float* __restrict__ Hs,
                                                    const int* __restrict__ rowptr, const int* __restrict__ srcs,
                                                    const float* __restrict__ eas, const float* __restrict__ w1e,
                                                    float* __restrict__ esum, float* __restrict__ esq, int n) {
    __shared__ float rs[4][64], rq[4][64];
    int wid = threadIdx.x >> 6, lane = threadIdx.x & 63;
    int gw = (blockIdx.x * 256 + threadIdx.x) >> 6;
    int nw = (gridDim.x * 256) >> 6;
    float wj = w1e[lane];
    float s = 0.0f, q = 0.0f;
    for (int node = gw; node < n; node += nw) {
        int e0 = rowptr[node], e1 = rowptr[node + 1];
        if (e0 == e1) continue;
        float hd = Hd[(size_t)node * 64 + lane];
        for (int e = e0; e < e1; e++) {
            int sidx = srcs[e];
            float ea = eas[e];
            float z = hd + Hs[(size_t)sidx * 64 + lane] + ea * wj;
            s += z;
            q = fmaf(z, z, q);
        }
    }
    rs[wid][lane] = s; rq[wid][lane] = q;
    __syncthreads();
    if (wid == 0) {
        float ts = rs[0][lane] + rs[1][lane] + rs[2][lane] + rs[3][lane];
        float tq = rq[0][lane] + rq[1][lane] + rq[2][lane] + rq[3][lane];
        atomicAdd(&esum[lane], ts);
        atomicAdd(&esq[lane], tq);
    }
}

// ---------- edge pass 2: sacc[n] = (sum_in silu(bn(z))) / deg ----------
__global__ __launch_bounds__(256) void k_edge_agg(const float* __restrict__ Hd, const float* __restrict__ Hs,
                                                  const int* __restrict__ rowptr, const int* __restrict__ srcs,
                                                  const float* __restrict__ eas, const float* __restrict__ w1e,
                                                  const float* __restrict__ esum, const float* __restrict__ esq,
                                                  const float* __restrict__ g1, const float* __restrict__ be1,
                                                  const float* __restrict__ degf, float* __restrict__ sacc,
                                                  int n, float invE) {
    int lane = threadIdx.x & 63;
    float mean = esum[lane] * invE;
    float var = esq[lane] * invE - mean * mean;
    float inv = rsqrtf(var + 1e-5f);
    float sc = inv * g1[lane];
    float sh = fmaf(-mean, sc, be1[lane]);
    float wj = w1e[lane];
    int gw = (blockIdx.x * 256 + threadIdx.x) >> 6;
    int nw = (gridDim.x * 256) >> 6;
    for (int node = gw; node < n; node += nw) {
        int e0 = rowptr[node], e1 = rowptr[node + 1];
        float acc = 0.0f;
        float hd = Hd[(size_t)node * 64 + lane];
        for (int e = e0; e < e1; e++) {
            int sidx = srcs[e];
            float ea = eas[e];
            float z = hd + Hs[(size_t)sidx * 64 + lane] + ea * wj;
            float y = fmaf(z, sc, sh);
            acc += silu_f(y);
        }
        sacc[(size_t)node * 64 + lane] = acc / degf[node];
    }
}

// ---------- node update: t = sacc@W2 + 1{cnt>0} b2 ; u = h@U1 + t@U2 + ub ; stats(u) ----------
__global__ __launch_bounds__(256) void k_node_upd(const float* __restrict__ h, const float* __restrict__ sacc,
                                                  const float* __restrict__ W2, const float* __restrict__ b2,
                                                  const float* __restrict__ U, const float* __restrict__ ub,
                                                  const int* __restrict__ rowptr, float* __restrict__ u,
                                                  float* __restrict__ usum, float* __restrict__ usq, int n) {
    __shared__ float sW2[4096], sU1[4096], sU2[4096];
    __shared__ float rs[4][64], rq[4][64];
    for (int i = threadIdx.x; i < 4096; i += 256) { sW2[i] = W2[i]; sU1[i] = U[i]; sU2[i] = U[4096 + i]; }
    __syncthreads();
    int wid = threadIdx.x >> 6, lane = threadIdx.x & 63;
    int gw = (blockIdx.x * 256 + threadIdx.x) >> 6;
    int nw = (gridDim.x * 256) >> 6;
    float b2j = b2[lane], ubj = ub[lane];
    float s = 0.0f, q = 0.0f;
    for (int node = gw; node < n; node += nw) {
        float sv = sacc[(size_t)node * 64 + lane];
        float hv = h[(size_t)node * 64 + lane];
        int cnt = rowptr[node + 1] - rowptr[node];
        float t = (cnt > 0) ? b2j : 0.0f;
        #pragma unroll
        for (int m = 0; m < 64; m++) t = fmaf(__shfl(sv, m), sW2[m * 64 + lane], t);
        float acc = ubj;
        #pragma unroll
        for (int k = 0; k < 64; k++) {
            acc = fmaf(__shfl(hv, k), sU1[k * 64 + lane], acc);
            acc = fmaf(__shfl(t, k), sU2[k * 64 + lane], acc);
        }
        u[(size_t)node * 64 + lane] = acc;
        s += acc;
        q = fmaf(acc, acc, q);
    }
    rs[wid][lane] = s; rq[wid][lane] = q;
    __syncthreads();
    if (wid == 0) {
        float ts = rs[0][lane] + rs[1][lane] + rs[2][lane] + rs[3][lane];
        float tq = rq[0][lane] + rq[1][lane] + rq[2][lane] + rq[3][lane];
        atomicAdd(&usum[lane], ts);
        atomicAdd(&usq[lane], tq);
    }
}

// ---------- node BN + SiLU: h = silu(u*scale + shift) ----------
__global__ __launch_bounds__(256) void k_node_bn(const float* __restrict__ u, const float* __restrict__ usum,
                                                 const float* __restrict__ usq, const float* __restrict__ g,
                                                 const float* __restrict__ be, float* __restrict__ h,
                                                 int n, float invN) {
    __shared__ float ssc[64], ssh[64];
    if (threadIdx.x < 64) {
        int j = threadIdx.x;
        float mean = usum[j] * invN;
        float var = usq[j] * invN - mean * mean;
        float inv = rsqrtf(var + 1e-5f);
        float sc = inv * g[j];
        ssc[j] = sc;
        ssh[j] = fmaf(-mean, sc, be[j]);
    }
    __syncthreads();
    int total = n * 64;
    for (int i = blockIdx.x * 256 + threadIdx.x; i < total; i += gridDim.x * 256) {
        int j = i & 63;
        float y = fmaf(u[i], ssc[j], ssh[j]);
        h[i] = silu_f(y);
    }
}

// ---------- pooling: per-graph sums (batch sorted -> local run accumulation) ----------
__global__ __launch_bounds__(256) void k_pool(const float* __restrict__ h, const int* __restrict__ batch,
                                              float* __restrict__ gsum, float* __restrict__ gcnt, int n) {
    int lane = threadIdx.x & 63;
    int gw = (blockIdx.x * 256 + threadIdx.x) >> 6;
    int nw = (gridDim.x * 256) >> 6;
    int per = (n + nw - 1) / nw;
    int start = gw * per;
    int end = start + per; if (end > n) end = n;
    if (start >= end) return;
    int cur = batch[start];
    float acc = 0.0f, c = 0.0f;
    for (int i = start; i < end; i++) {
        int b = batch[i];
        if (b != cur) {
            atomicAdd(&gsum[(size_t)cur * 64 + lane], acc);
            if (lane == 0) atomicAdd(&gcnt[cur], c);
            cur = b; acc = 0.0f; c = 0.0f;
        }
        acc += h[(size_t)i * 64 + lane];
        c += 1.0f;
    }
    atomicAdd(&gsum[(size_t)cur * 64 + lane], acc);
    if (lane == 0) atomicAdd(&gcnt[cur], c);
}

// ---------- output: silu((gsum/cnt) @ out_W + out_b) ----------
__global__ __launch_bounds__(256) void k_out(const float* __restrict__ gsum, const float* __restrict__ gcnt,
                                             const float* __restrict__ OW, const float* __restrict__ ob,
                                             float* __restrict__ out, int G) {
    __shared__ float sW[4096];
    for (int i = threadIdx.x; i < 4096; i += 256) sW[i] = OW[i];
    __syncthreads();
    int lane = threadIdx.x & 63;
    int gw = (blockIdx.x * 256 + threadIdx.x) >> 6;
    int nw = (gridDim.x * 256) >> 6;
    for (int g = gw; g < G; g += nw) {
        float c = gcnt[g]; if (c < 1.0f) c = 1.0f;
        float gv = gsum[(size_t)g * 64 + lane] / c;
        float acc = ob[lane];
        #pragma unroll
        for (int k = 0; k < 64; k++) acc = fmaf(__shfl(gv, k), sW[k * 64 + lane], acc);
        out[(size_t)g * 64 + lane] = silu_f(acc);
    }
}

extern "C" void kernel_launch(void* const* d_in, const int* in_sizes, int n_in,
                              void* d_out, int out_size, void* d_ws, size_t ws_size,
                              hipStream_t stream) {
    const int N = NN, E = EE, G = GG, L = LL;
    const float* x         = (const float*)d_in[0];
    const float* edge_attr = (const float*)d_in[1];
    const int*   edge_index= (const int*)d_in[2];
    const int*   batch     = (const int*)d_in[3];
    const float* node_W    = (const float*)d_in[4];
    const float* node_b    = (const float*)d_in[5];
    const float* msg_W1    = (const float*)d_in[6];
    const float* msg_b1    = (const float*)d_in[7];
    const float* msg_g1    = (const float*)d_in[8];
    const float* msg_be1   = (const float*)d_in[9];
    const float* msg_W2    = (const float*)d_in[10];
    const float* msg_b2    = (const float*)d_in[11];
    const float* upd_W     = (const float*)d_in[12];
    const float* upd_b     = (const float*)d_in[13];
    const float* upd_g     = (const float*)d_in[14];
    const float* upd_be    = (const float*)d_in[15];
    const float* out_W     = (const float*)d_in[16];
    const float* out_b     = (const float*)d_in[17];
    float* out = (float*)d_out;

    char* ws = (char*)d_ws;
    size_t off = 0;
    auto alloc = [&](size_t b) { size_t o = off; off = (off + b + 255) & ~(size_t)255; return o; };
    float* h    = (float*)(ws + alloc((size_t)N * 64 * 4));
    float* Hd   = (float*)(ws + alloc((size_t)N * 64 * 4));   // reused as u
    float* Hs   = (float*)(ws + alloc((size_t)N * 64 * 4));
    float* sacc = (float*)(ws + alloc((size_t)N * 64 * 4));
    int*   srcs = (int*)  (ws + alloc((size_t)E * 4));
    float* eas  = (float*)(ws + alloc((size_t)E * 4));
    int* rowptr = (int*)  (ws + alloc((size_t)(N + 1) * 4));
    int*   fill = (int*)  (ws + alloc((size_t)N * 4));
    float* degf = (float*)(ws + alloc((size_t)N * 4));
    float* stats= (float*)(ws + alloc(4 * 64 * 4));
    float* gsum = (float*)(ws + alloc((size_t)(G * 64 + G) * 4));
    float* gcnt = gsum + (size_t)G * 64;
    float* u = Hd;
    float* esum = stats, *esq = stats + 64, *usum = stats + 128, *usq = stats + 192;

    // CSR build
    hipMemsetAsync(fill, 0, (size_t)N * 4, stream);
    k_hist<<<(E + 255) / 256, 256, 0, stream>>>(edge_index, fill, E);
    k_scan<<<1, 1024, 0, stream>>>(fill, rowptr, degf, fill, N);
    k_scatter<<<(E + 255) / 256, 256, 0, stream>>>(edge_index, edge_attr, rowptr, fill, srcs, eas, E);

    // node embedding
    k_node_emb<<<1024, 256, 0, stream>>>(x, node_W, node_b, h, N);

    for (int l = 0; l < L; l++) {
        const float* W1  = msg_W1 + (size_t)l * 129 * 64;
        const float* w1e = W1 + 128 * 64;
        hipMemsetAsync(stats, 0, 4 * 64 * 4, stream);
        k_node_pre<<<1024, 256, 0, stream>>>(h, W1, msg_b1 + l * 64, Hd, Hs, N);
        k_edge_stats<<<1024, 256, 0, stream>>>(Hd, Hs, rowptr, srcs, eas, w1e, esum, esq, N);
        k_edge_agg<<<1024, 256, 0, stream>>>(Hd, Hs, rowptr, srcs, eas, w1e, esum, esq,
                                             msg_g1 + l * 64, msg_be1 + l * 64, degf, sacc, N, 1.0f / E);
        k_node_upd<<<1024, 256, 0, stream>>>(h, sacc, msg_W2 + (size_t)l * 4096, msg_b2 + l * 64,
                                             upd_W + (size_t)l * 8192, upd_b + l * 64, rowptr,
                                             u, usum, usq, N);
        k_node_bn<<<2048, 256, 0, stream>>>(u, usum, usq, upd_g + l * 64, upd_be + l * 64, h, N, 1.0f / N);
    }

    hipMemsetAsync(gsum, 0, (size_t)(G * 64 + G) * 4, stream);
    k_pool<<<256, 256, 0, stream>>>(h, batch, gsum, gcnt, N);
    k_out<<<64, 256, 0, stream>>>(gsum, gcnt, out_W, out_b, out, G);
}

// Round 2
// 1636.645 us; speedup vs baseline: 2.5743x; 2.5743x over previous
//
#include <hip/hip_runtime.h>
#include <hip/hip_bf16.h>

#define NN 50000
#define EE 1200000
#define GG 256
#define LL 5

__device__ __forceinline__ float silu_f(float x) { return x / (1.0f + expf(-x)); }
__device__ __forceinline__ int rfl(int x) { return __builtin_amdgcn_readfirstlane(x); }

// ---------- CSR build ----------
__global__ __launch_bounds__(256) void k_hist(const int* __restrict__ ei, int* __restrict__ fill, int E) {
    int e = blockIdx.x * 256 + threadIdx.x;
    if (e < E) atomicAdd(&fill[ei[E + e]], 1);
}

__global__ __launch_bounds__(1024) void k_scan(const int* __restrict__ cnt, int* __restrict__ rowptr,
                                               float* __restrict__ degf, int* __restrict__ fill, int n) {
    __shared__ int wsum[16];
    __shared__ int carry_s;
    int tid = threadIdx.x, lane = tid & 63, wid = tid >> 6;
    if (tid == 0) carry_s = 0;
    __syncthreads();
    for (int base = 0; base < n; base += 1024) {
        int i = base + tid;
        int v = (i < n) ? cnt[i] : 0;
        int x = v;
        #pragma unroll
        for (int off = 1; off < 64; off <<= 1) {
            int t = __shfl_up(x, off);
            if (lane >= off) x += t;
        }
        if (lane == 63) wsum[wid] = x;
        __syncthreads();
        if (wid == 0 && lane < 16) {
            int w = wsum[lane];
            #pragma unroll
            for (int off = 1; off < 16; off <<= 1) {
                int t = __shfl_up(w, off);
                if (lane >= off) w += t;
            }
            wsum[lane] = w;
        }
        __syncthreads();
        int waveoff = (wid == 0) ? 0 : wsum[wid - 1];
        int inc = x + waveoff;
        int c = carry_s;
        int chunk_total = wsum[15];
        __syncthreads();
        if (i < n) {
            rowptr[i + 1] = c + inc;
            degf[i] = (float)(v > 0 ? v : 1);
            fill[i] = 0;
        }
        if (tid == 0) {
            if (base == 0) rowptr[0] = 0;
            carry_s = c + chunk_total;
        }
        __syncthreads();
    }
}

__global__ __launch_bounds__(256) void k_scatter(const int* __restrict__ ei, const float* __restrict__ ea,
                                                 const int* __restrict__ rowptr, int* __restrict__ fill,
                                                 int* __restrict__ srcs, float* __restrict__ eas, int E) {
    int e = blockIdx.x * 256 + threadIdx.x;
    if (e < E) {
        int d = ei[E + e];
        int pos = atomicAdd(&fill[d], 1);
        int idx = rowptr[d] + pos;
        srcs[idx] = ei[e];
        eas[idx] = ea[e];
    }
}

// ---------- weight fold: W2p[l] = msg_W2[l] @ U2[l], b2p[l] = msg_b2[l] @ U2[l] ----------
__global__ __launch_bounds__(256) void k_fold(const float* __restrict__ msg_W2, const float* __restrict__ msg_b2,
                                              const float* __restrict__ upd_W, float* __restrict__ W2p,
                                              float* __restrict__ b2p) {
    int l = blockIdx.x;
    const float* W2 = msg_W2 + (size_t)l * 4096;
    const float* U2 = upd_W + (size_t)l * 8192 + 4096;
    int lane = threadIdx.x & 63, wid = threadIdx.x >> 6;
    for (int ii = 0; ii < 16; ii++) {
        int i = rfl(wid * 16 + ii);
        float acc = 0.0f;
        for (int k = 0; k < 64; k++) acc = fmaf(W2[i * 64 + k], U2[k * 64 + lane], acc);
        W2p[(size_t)l * 4096 + i * 64 + lane] = acc;
    }
    if (wid == 0) {
        float acc = 0.0f;
        for (int k = 0; k < 64; k++) acc = fmaf(msg_b2[l * 64 + k], U2[k * 64 + lane], acc);
        b2p[l * 64 + lane] = acc;
    }
}

// ---------- node embedding: h = x @ node_W + node_b  (x: [N,92]), R=8 row tile, scalar broadcasts ----------
__global__ __launch_bounds__(256) void k_node_emb(const float* __restrict__ x, const float* __restrict__ W,
                                                  const float* __restrict__ b, float* __restrict__ h, int n) {
    __shared__ float sW[92 * 64];
    for (int i = threadIdx.x; i < 92 * 64; i += 256) sW[i] = W[i];
    __syncthreads();
    int lane = threadIdx.x & 63;
    int gw = (blockIdx.x * 256 + threadIdx.x) >> 6;
    int nw = (gridDim.x * 256) >> 6;
    float bj = b[lane];
    int tiles = n >> 3;  // n % 8 == 0
    for (int t = gw; t < tiles; t += nw) {
        int rb = rfl(t << 3);
        float acc[8];
        #pragma unroll
        for (int r = 0; r < 8; r++) acc[r] = bj;
        for (int kb = 0; kb < 80; kb += 16) {
            float wv[16];
            #pragma unroll
            for (int t2 = 0; t2 < 16; t2++) wv[t2] = sW[(kb + t2) * 64 + lane];
            #pragma unroll
            for (int r = 0; r < 8; r++) {
                const float* xr = x + (size_t)(rb + r) * 92 + kb;
                #pragma unroll
                for (int t2 = 0; t2 < 16; t2++) acc[r] = fmaf(xr[t2], wv[t2], acc[r]);
            }
        }
        {   // tail: k = 80..91
            float wv[12];
            #pragma unroll
            for (int t2 = 0; t2 < 12; t2++) wv[t2] = sW[(80 + t2) * 64 + lane];
            #pragma unroll
            for (int r = 0; r < 8; r++) {
                const float* xr = x + (size_t)(rb + r) * 92 + 80;
                #pragma unroll
                for (int t2 = 0; t2 < 12; t2++) acc[r] = fmaf(xr[t2], wv[t2], acc[r]);
            }
        }
        #pragma unroll
        for (int r = 0; r < 8; r++) h[(size_t)(rb + r) * 64 + lane] = acc[r];
    }
}

// ---------- per-layer: Hd = h@W1[0:64] + b1 ; Hs = h@W1[64:128] — R=8, scalar broadcasts ----------
__global__ __launch_bounds__(256) void k_node_pre(const float* __restrict__ h, const float* __restrict__ W1,
                                                  const float* __restrict__ b1, float* __restrict__ Hd,
                                                  float* __restrict__ Hs, int n) {
    __shared__ float sA[4096], sB[4096];
    for (int i = threadIdx.x; i < 4096; i += 256) { sA[i] = W1[i]; sB[i] = W1[4096 + i]; }
    __syncthreads();
    int lane = threadIdx.x & 63;
    int gw = (blockIdx.x * 256 + threadIdx.x) >> 6;
    int nw = (gridDim.x * 256) >> 6;
    float bj = b1[lane];
    int tiles = n >> 3;
    for (int t = gw; t < tiles; t += nw) {
        int rb = rfl(t << 3);
        float accA[8], accB[8];
        #pragma unroll
        for (int r = 0; r < 8; r++) { accA[r] = bj; accB[r] = 0.0f; }
        for (int kb = 0; kb < 64; kb += 16) {
            float wA[16], wB[16];
            #pragma unroll
            for (int t2 = 0; t2 < 16; t2++) { wA[t2] = sA[(kb + t2) * 64 + lane]; wB[t2] = sB[(kb + t2) * 64 + lane]; }
            #pragma unroll
            for (int r = 0; r < 8; r++) {
                const float* hr = h + (size_t)(rb + r) * 64 + kb;
                #pragma unroll
                for (int t2 = 0; t2 < 16; t2++) {
                    float hk = hr[t2];
                    accA[r] = fmaf(hk, wA[t2], accA[r]);
                    accB[r] = fmaf(hk, wB[t2], accB[r]);
                }
            }
        }
        #pragma unroll
        for (int r = 0; r < 8; r++) {
            Hd[(size_t)(rb + r) * 64 + lane] = accA[r];
            Hs[(size_t)(rb + r) * 64 + lane] = accB[r];
        }
    }
}

// ---------- edge pass 1: accumulate sum(z), sum(z^2) per column, 4x unrolled ----------
__global__ __launch_bounds__(256) void k_edge_stats(const float* __restrict__ Hd, const float* __restrict__ Hs,
                                                    const int* __restrict__ rowptr, const int* __restrict__ srcs,
                                                    const float* __restrict__ eas, const float* __restrict__ w1e,
                                                    float* __restrict__ esum, float* __restrict__ esq, int n) {
    __shared__ float rs[4][64], rq[4][64];
    int wid = threadIdx.x >> 6, lane = threadIdx.x & 63;
    int gw = (blockIdx.x * 256 + threadIdx.x) >> 6;
    int nw = (gridDim.x * 256) >> 6;
    float wj = w1e[lane];
    float s = 0.0f, q = 0.0f;
    for (int node = gw; node < n; node += nw) {
        int nu = rfl(node);
        int e0 = rowptr[nu], e1 = rowptr[nu + 1];
        if (e0 == e1) continue;
        float hd = Hd[(size_t)nu * 64 + lane];
        int e = e0;
        for (; e + 4 <= e1; e += 4) {
            int s0 = srcs[e], s1 = srcs[e + 1], s2 = srcs[e + 2], s3 = srcs[e + 3];
            float a0 = eas[e], a1 = eas[e + 1], a2 = eas[e + 2], a3 = eas[e + 3];
            float z0 = hd + Hs[(size_t)s0 * 64 + lane] + a0 * wj;
            float z1 = hd + Hs[(size_t)s1 * 64 + lane] + a1 * wj;
            float z2 = hd + Hs[(size_t)s2 * 64 + lane] + a2 * wj;
            float z3 = hd + Hs[(size_t)s3 * 64 + lane] + a3 * wj;
            s += z0 + z1 + z2 + z3;
            q = fmaf(z0, z0, q); q = fmaf(z1, z1, q); q = fmaf(z2, z2, q); q = fmaf(z3, z3, q);
        }
        for (; e < e1; e++) {
            int si = srcs[e];
            float z = hd + Hs[(size_t)si * 64 + lane] + eas[e] * wj;
            s += z;
            q = fmaf(z, z, q);
        }
    }
    rs[wid][lane] = s; rq[wid][lane] = q;
    __syncthreads();
    if (wid == 0) {
        float ts = rs[0][lane] + rs[1][lane] + rs[2][lane] + rs[3][lane];
        float tq = rq[0][lane] + rq[1][lane] + rq[2][lane] + rq[3][lane];
        atomicAdd(&esum[lane], ts);
        atomicAdd(&esq[lane], tq);
    }
}

// ---------- edge pass 2: sacc[n] = (sum_in silu(bn(z))) / deg, 4x unrolled ----------
__global__ __launch_bounds__(256) void k_edge_agg(const float* __restrict__ Hd, const float* __restrict__ Hs,
                                                  const int* __restrict__ rowptr, const int* __restrict__ srcs,
                                                  const float* __restrict__ eas, const float* __restrict__ w1e,
                                                  const float* __restrict__ esum, const float* __restrict__ esq,
                                                  const float* __restrict__ g1, const float* __restrict__ be1,
                                                  const float* __restrict__ degf, float* __restrict__ sacc,
                                                  int n, float invE) {
    int lane = threadIdx.x & 63;
    float mean = esum[lane] * invE;
    float var = esq[lane] * invE - mean * mean;
    float inv = rsqrtf(var + 1e-5f);
    float sc = inv * g1[lane];
    float sh = fmaf(-mean, sc, be1[lane]);
    float wj = w1e[lane];
    int gw = (blockIdx.x * 256 + threadIdx.x) >> 6;
    int nw = (gridDim.x * 256) >> 6;
    for (int node = gw; node < n; node += nw) {
        int nu = rfl(node);
        int e0 = rowptr[nu], e1 = rowptr[nu + 1];
        float acc = 0.0f;
        float hd = Hd[(size_t)nu * 64 + lane];
        int e = e0;
        for (; e + 4 <= e1; e += 4) {
            int s0 = srcs[e], s1 = srcs[e + 1], s2 = srcs[e + 2], s3 = srcs[e + 3];
            float a0 = eas[e], a1 = eas[e + 1], a2 = eas[e + 2], a3 = eas[e + 3];
            float z0 = hd + Hs[(size_t)s0 * 64 + lane] + a0 * wj;
            float z1 = hd + Hs[(size_t)s1 * 64 + lane] + a1 * wj;
            float z2 = hd + Hs[(size_t)s2 * 64 + lane] + a2 * wj;
            float z3 = hd + Hs[(size_t)s3 * 64 + lane] + a3 * wj;
            acc += silu_f(fmaf(z0, sc, sh)) + silu_f(fmaf(z1, sc, sh))
                 + silu_f(fmaf(z2, sc, sh)) + silu_f(fmaf(z3, sc, sh));
        }
        for (; e < e1; e++) {
            int si = srcs[e];
            float z = hd + Hs[(size_t)si * 64 + lane] + eas[e] * wj;
            acc += silu_f(fmaf(z, sc, sh));
        }
        sacc[(size_t)nu * 64 + lane] = acc / degf[nu];
    }
}

// ---------- node update: u = h@U1 + sacc@W2p + gate*b2p + ub ; stats(u). R=8, scalar broadcasts ----------
__global__ __launch_bounds__(256) void k_node_upd(const float* __restrict__ h, const float* __restrict__ sacc,
                                                  const float* __restrict__ U1, const float* __restrict__ W2p,
                                                  const float* __restrict__ b2p, const float* __restrict__ ub,
                                                  const int* __restrict__ rowptr, float* __restrict__ u,
                                                  float* __restrict__ usum, float* __restrict__ usq, int n) {
    __shared__ float sU[4096], sP[4096];
    __shared__ float rs[4][64], rq[4][64];
    for (int i = threadIdx.x; i < 4096; i += 256) { sU[i] = U1[i]; sP[i] = W2p[i]; }
    __syncthreads();
    int wid = threadIdx.x >> 6, lane = threadIdx.x & 63;
    int gw = (blockIdx.x * 256 + threadIdx.x) >> 6;
    int nw = (gridDim.x * 256) >> 6;
    float b2j = b2p[lane], ubj = ub[lane];
    float s = 0.0f, q = 0.0f;
    int tiles = n >> 3;
    for (int t = gw; t < tiles; t += nw) {
        int rb = rfl(t << 3);
        float acc[8];
        #pragma unroll
        for (int r = 0; r < 8; r++) {
            int c0 = rowptr[rb + r], c1 = rowptr[rb + r + 1];
            acc[r] = ubj + (c1 > c0 ? b2j : 0.0f);
        }
        for (int kb = 0; kb < 64; kb += 16) {
            float wU[16], wP[16];
            #pragma unroll
            for (int t2 = 0; t2 < 16; t2++) { wU[t2] = sU[(kb + t2) * 64 + lane]; wP[t2] = sP[(kb + t2) * 64 + lane]; }
            #pragma unroll
            for (int r = 0; r < 8; r++) {
                const float* hr = h + (size_t)(rb + r) * 64 + kb;
                const float* sr = sacc + (size_t)(rb + r) * 64 + kb;
                #pragma unroll
                for (int t2 = 0; t2 < 16; t2++) {
                    acc[r] = fmaf(hr[t2], wU[t2], acc[r]);
                    acc[r] = fmaf(sr[t2], wP[t2], acc[r]);
                }
            }
        }
        #pragma unroll
        for (int r = 0; r < 8; r++) {
            u[(size_t)(rb + r) * 64 + lane] = acc[r];
            s += acc[r];
            q = fmaf(acc[r], acc[r], q);
        }
    }
    rs[wid][lane] = s; rq[wid][lane] = q;
    __syncthreads();
    if (wid == 0) {
        float ts = rs[0][lane] + rs[1][lane] + rs[2][lane] + rs[3][lane];
        float tq = rq[0][lane] + rq[1][lane] + rq[2][lane] + rq[3][lane];
        atomicAdd(&usum[lane], ts);
        atomicAdd(&usq[lane], tq);
    }
}

// ---------- node BN + SiLU: h = silu(u*scale + shift) ----------
__global__ __launch_bounds__(256) void k_node_bn(const float* __restrict__ u, const float* __restrict__ usum,
                                                 const float* __restrict__ usq, const float* __restrict__ g,
                                                 const float* __restrict__ be, float* __restrict__ h,
                                                 int n, float invN) {
    __shared__ float ssc[64], ssh[64];
    if (threadIdx.x < 64) {
        int j = threadIdx.x;
        float mean = usum[j] * invN;
        float var = usq[j] * invN - mean * mean;
        float inv = rsqrtf(var + 1e-5f);
        float sc = inv * g[j];
        ssc[j] = sc;
        ssh[j] = fmaf(-mean, sc, be[j]);
    }
    __syncthreads();
    int total = n * 64;
    for (int i = blockIdx.x * 256 + threadIdx.x; i < total; i += gridDim.x * 256) {
        int j = i & 63;
        float y = fmaf(u[i], ssc[j], ssh[j]);
        h[i] = silu_f(y);
    }
}

// ---------- pooling ----------
__global__ __launch_bounds__(256) void k_pool(const float* __restrict__ h, const int* __restrict__ batch,
                                              float* __restrict__ gsum, float* __restrict__ gcnt, int n) {
    int lane = threadIdx.x & 63;
    int gw = (blockIdx.x * 256 + threadIdx.x) >> 6;
    int nw = (gridDim.x * 256) >> 6;
    int per = (n + nw - 1) / nw;
    int start = gw * per;
    int end = start + per; if (end > n) end = n;
    if (start >= end) return;
    int cur = batch[start];
    float acc = 0.0f, c = 0.0f;
    for (int i = start; i < end; i++) {
        int b = batch[i];
        if (b != cur) {
            atomicAdd(&gsum[(size_t)cur * 64 + lane], acc);
            if (lane == 0) atomicAdd(&gcnt[cur], c);
            cur = b; acc = 0.0f; c = 0.0f;
        }
        acc += h[(size_t)i * 64 + lane];
        c += 1.0f;
    }
    atomicAdd(&gsum[(size_t)cur * 64 + lane], acc);
    if (lane == 0) atomicAdd(&gcnt[cur], c);
}

// ---------- output: silu((gsum/cnt) @ out_W + out_b) ----------
__global__ __launch_bounds__(256) void k_out(const float* __restrict__ gsum, const float* __restrict__ gcnt,
                                             const float* __restrict__ OW, const float* __restrict__ ob,
                                             float* __restrict__ out, int G) {
    __shared__ float sW[4096];
    for (int i = threadIdx.x; i < 4096; i += 256) sW[i] = OW[i];
    __syncthreads();
    int lane = threadIdx.x & 63;
    int gw = (blockIdx.x * 256 + threadIdx.x) >> 6;
    int nw = (gridDim.x * 256) >> 6;
    for (int g = gw; g < G; g += nw) {
        int gu = rfl(g);
        float c = gcnt[gu]; if (c < 1.0f) c = 1.0f;
        float ci = 1.0f / c;
        float acc = ob[lane];
        const float* gr = gsum + (size_t)gu * 64;
        #pragma unroll
        for (int k = 0; k < 64; k++) acc = fmaf(gr[k] * ci, sW[k * 64 + lane], acc);
        out[(size_t)gu * 64 + lane] = silu_f(acc);
    }
}

extern "C" void kernel_launch(void* const* d_in, const int* in_sizes, int n_in,
                              void* d_out, int out_size, void* d_ws, size_t ws_size,
                              hipStream_t stream) {
    const int N = NN, E = EE, G = GG, L = LL;
    const float* x         = (const float*)d_in[0];
    const float* edge_attr = (const float*)d_in[1];
    const int*   edge_index= (const int*)d_in[2];
    const int*   batch     = (const int*)d_in[3];
    const float* node_W    = (const float*)d_in[4];
    const float* node_b    = (const float*)d_in[5];
    const float* msg_W1    = (const float*)d_in[6];
    const float* msg_b1    = (const float*)d_in[7];
    const float* msg_g1    = (const float*)d_in[8];
    const float* msg_be1   = (const float*)d_in[9];
    const float* msg_W2    = (const float*)d_in[10];
    const float* msg_b2    = (const float*)d_in[11];
    const float* upd_W     = (const float*)d_in[12];
    const float* upd_b     = (const float*)d_in[13];
    const float* upd_g     = (const float*)d_in[14];
    const float* upd_be    = (const float*)d_in[15];
    const float* out_W     = (const float*)d_in[16];
    const float* out_b     = (const float*)d_in[17];
    float* out = (float*)d_out;

    char* ws = (char*)d_ws;
    size_t off = 0;
    auto alloc = [&](size_t b) { size_t o = off; off = (off + b + 255) & ~(size_t)255; return o; };
    float* h    = (float*)(ws + alloc((size_t)N * 64 * 4));
    float* Hd   = (float*)(ws + alloc((size_t)N * 64 * 4));   // reused as u
    float* Hs   = (float*)(ws + alloc((size_t)N * 64 * 4));
    float* sacc = (float*)(ws + alloc((size_t)N * 64 * 4));
    int*   srcs = (int*)  (ws + alloc((size_t)E * 4));
    float* eas  = (float*)(ws + alloc((size_t)E * 4));
    int* rowptr = (int*)  (ws + alloc((size_t)(N + 1) * 4));
    float* degf = (float*)(ws + alloc((size_t)N * 4));
    float* W2p  = (float*)(ws + alloc((size_t)L * 4096 * 4));
    float* b2p  = (float*)(ws + alloc((size_t)L * 64 * 4));
    // zero-init region: fill + stats + gsum/gcnt — contiguous, single memset
    size_t zero_begin = off;
    int*   fill = (int*)  (ws + alloc((size_t)N * 4));
    float* stats= (float*)(ws + alloc((size_t)L * 4 * 64 * 4));  // per layer: esum,esq,usum,usq
    float* gsum = (float*)(ws + alloc((size_t)(G * 64 + G) * 4));
    size_t zero_end = off;
    float* gcnt = gsum + (size_t)G * 64;
    float* u = Hd;

    hipMemsetAsync(ws + zero_begin, 0, zero_end - zero_begin, stream);

    // CSR build
    k_hist<<<(E + 255) / 256, 256, 0, stream>>>(edge_index, fill, E);
    k_scan<<<1, 1024, 0, stream>>>(fill, rowptr, degf, fill, N);
    k_scatter<<<(E + 255) / 256, 256, 0, stream>>>(edge_index, edge_attr, rowptr, fill, srcs, eas, E);

    // weight fold + node embedding
    k_fold<<<L, 256, 0, stream>>>(msg_W2, msg_b2, upd_W, W2p, b2p);
    k_node_emb<<<1024, 256, 0, stream>>>(x, node_W, node_b, h, N);

    for (int l = 0; l < L; l++) {
        const float* W1  = msg_W1 + (size_t)l * 129 * 64;
        const float* w1e = W1 + 128 * 64;
        float* esum = stats + (size_t)l * 256;
        float* esq  = esum + 64;
        float* usum = esum + 128;
        float* usq  = esum + 192;
        k_node_pre<<<1024, 256, 0, stream>>>(h, W1, msg_b1 + l * 64, Hd, Hs, N);
        k_edge_stats<<<2048, 256, 0, stream>>>(Hd, Hs, rowptr, srcs, eas, w1e, esum, esq, N);
        k_edge_agg<<<2048, 256, 0, stream>>>(Hd, Hs, rowptr, srcs, eas, w1e, esum, esq,
                                             msg_g1 + l * 64, msg_be1 + l * 64, degf, sacc, N, 1.0f / E);
        k_node_upd<<<1024, 256, 0, stream>>>(h, sacc, upd_W + (size_t)l * 8192, W2p + (size_t)l * 4096,
                                             b2p + (size_t)l * 64, upd_b + l * 64, rowptr,
                                             u, usum, usq, N);
        k_node_bn<<<2048, 256, 0, stream>>>(u, usum, usq, upd_g + l * 64, upd_be + l * 64, h, N, 1.0f / N);
    }

    k_pool<<<256, 256, 0, stream>>>(h, batch, gsum, gcnt, N);
    k_out<<<64, 256, 0, stream>>>(gsum, gcnt, out_W, out_b, out, G);
}

// Round 4
// 1635.235 us; speedup vs baseline: 2.5765x; 1.0009x over previous
//
#include <hip/hip_runtime.h>
#include <hip/hip_bf16.h>

#define NN 50000
#define EE 1200000
#define GG 256
#define LL 5

__device__ __forceinline__ float silu_f(float x) { return x / (1.0f + expf(-x)); }
__device__ __forceinline__ int rfl(int x) { return __builtin_amdgcn_readfirstlane(x); }

// ---------- CSR build ----------
__global__ __launch_bounds__(256) void k_hist(const int* __restrict__ ei, int* __restrict__ fill, int E) {
    int e = blockIdx.x * 256 + threadIdx.x;
    if (e < E) atomicAdd(&fill[ei[E + e]], 1);
}

__global__ __launch_bounds__(1024) void k_scan(const int* __restrict__ cnt, int* __restrict__ rowptr,
                                               float* __restrict__ degf, int* __restrict__ fill, int n) {
    __shared__ int wsum[16];
    __shared__ int carry_s;
    int tid = threadIdx.x, lane = tid & 63, wid = tid >> 6;
    if (tid == 0) carry_s = 0;
    __syncthreads();
    for (int base = 0; base < n; base += 1024) {
        int i = base + tid;
        int v = (i < n) ? cnt[i] : 0;
        int x = v;
        #pragma unroll
        for (int off = 1; off < 64; off <<= 1) {
            int t = __shfl_up(x, off);
            if (lane >= off) x += t;
        }
        if (lane == 63) wsum[wid] = x;
        __syncthreads();
        if (wid == 0 && lane < 16) {
            int w = wsum[lane];
            #pragma unroll
            for (int off = 1; off < 16; off <<= 1) {
                int t = __shfl_up(w, off);
                if (lane >= off) w += t;
            }
            wsum[lane] = w;
        }
        __syncthreads();
        int waveoff = (wid == 0) ? 0 : wsum[wid - 1];
        int inc = x + waveoff;
        int c = carry_s;
        int chunk_total = wsum[15];
        __syncthreads();
        if (i < n) {
            rowptr[i + 1] = c + inc;
            degf[i] = (float)(v > 0 ? v : 1);
            fill[i] = 0;
        }
        if (tid == 0) {
            if (base == 0) rowptr[0] = 0;
            carry_s = c + chunk_total;
        }
        __syncthreads();
    }
}

// packed scatter: one 8B write per edge into edata = {src, ea_bits}
__global__ __launch_bounds__(256) void k_scatter(const int* __restrict__ ei, const float* __restrict__ ea,
                                                 const int* __restrict__ rowptr, int* __restrict__ fill,
                                                 int2* __restrict__ edata, int E) {
    int e = blockIdx.x * 256 + threadIdx.x;
    if (e < E) {
        int d = ei[E + e];
        int pos = atomicAdd(&fill[d], 1);
        int idx = rowptr[d] + pos;
        edata[idx] = make_int2(ei[e], __float_as_int(ea[e]));
    }
}

// ---------- weight fold: W2p[l] = msg_W2[l] @ U2[l], b2p[l] = msg_b2[l] @ U2[l] ----------
__global__ __launch_bounds__(256) void k_fold(const float* __restrict__ msg_W2, const float* __restrict__ msg_b2,
                                              const float* __restrict__ upd_W, float* __restrict__ W2p,
                                              float* __restrict__ b2p) {
    int l = blockIdx.x;
    const float* W2 = msg_W2 + (size_t)l * 4096;
    const float* U2 = upd_W + (size_t)l * 8192 + 4096;
    int lane = threadIdx.x & 63, wid = threadIdx.x >> 6;
    for (int ii = 0; ii < 16; ii++) {
        int i = rfl(wid * 16 + ii);
        float acc = 0.0f;
        for (int k = 0; k < 64; k++) acc = fmaf(W2[i * 64 + k], U2[k * 64 + lane], acc);
        W2p[(size_t)l * 4096 + i * 64 + lane] = acc;
    }
    if (wid == 0) {
        float acc = 0.0f;
        for (int k = 0; k < 64; k++) acc = fmaf(msg_b2[l * 64 + k], U2[k * 64 + lane], acc);
        b2p[l * 64 + lane] = acc;
    }
}

// ---------- node embedding: h = x @ node_W + node_b ----------
__global__ __launch_bounds__(256) void k_node_emb(const float* __restrict__ x, const float* __restrict__ W,
                                                  const float* __restrict__ b, float* __restrict__ h, int n) {
    __shared__ float sW[92 * 64];
    for (int i = threadIdx.x; i < 92 * 64; i += 256) sW[i] = W[i];
    __syncthreads();
    int lane = threadIdx.x & 63;
    int gw = (blockIdx.x * 256 + threadIdx.x) >> 6;
    int nw = (gridDim.x * 256) >> 6;
    float bj = b[lane];
    int tiles = n >> 3;
    for (int t = gw; t < tiles; t += nw) {
        int rb = rfl(t << 3);
        float acc[8];
        #pragma unroll
        for (int r = 0; r < 8; r++) acc[r] = bj;
        for (int kb = 0; kb < 80; kb += 16) {
            float wv[16];
            #pragma unroll
            for (int t2 = 0; t2 < 16; t2++) wv[t2] = sW[(kb + t2) * 64 + lane];
            #pragma unroll
            for (int r = 0; r < 8; r++) {
                const float* xr = x + (size_t)(rb + r) * 92 + kb;
                #pragma unroll
                for (int t2 = 0; t2 < 16; t2++) acc[r] = fmaf(xr[t2], wv[t2], acc[r]);
            }
        }
        {
            float wv[12];
            #pragma unroll
            for (int t2 = 0; t2 < 12; t2++) wv[t2] = sW[(80 + t2) * 64 + lane];
            #pragma unroll
            for (int r = 0; r < 8; r++) {
                const float* xr = x + (size_t)(rb + r) * 92 + 80;
                #pragma unroll
                for (int t2 = 0; t2 < 12; t2++) acc[r] = fmaf(xr[t2], wv[t2], acc[r]);
            }
        }
        #pragma unroll
        for (int r = 0; r < 8; r++) h[(size_t)(rb + r) * 64 + lane] = acc[r];
    }
}

// ---------- per-layer: Hd = h@W1[0:64] + b1 ; Hs = h@W1[64:128] (both fp32) ----------
__global__ __launch_bounds__(256) void k_node_pre(const float* __restrict__ h, const float* __restrict__ W1,
                                                  const float* __restrict__ b1, float* __restrict__ Hd,
                                                  float* __restrict__ Hs, int n) {
    __shared__ float sA[4096], sB[4096];
    for (int i = threadIdx.x; i < 4096; i += 256) { sA[i] = W1[i]; sB[i] = W1[4096 + i]; }
    __syncthreads();
    int lane = threadIdx.x & 63;
    int gw = (blockIdx.x * 256 + threadIdx.x) >> 6;
    int nw = (gridDim.x * 256) >> 6;
    float bj = b1[lane];
    int tiles = n >> 3;
    for (int t = gw; t < tiles; t += nw) {
        int rb = rfl(t << 3);
        float accA[8], accB[8];
        #pragma unroll
        for (int r = 0; r < 8; r++) { accA[r] = bj; accB[r] = 0.0f; }
        for (int kb = 0; kb < 64; kb += 16) {
            float wA[16], wB[16];
            #pragma unroll
            for (int t2 = 0; t2 < 16; t2++) { wA[t2] = sA[(kb + t2) * 64 + lane]; wB[t2] = sB[(kb + t2) * 64 + lane]; }
            #pragma unroll
            for (int r = 0; r < 8; r++) {
                const float* hr = h + (size_t)(rb + r) * 64 + kb;
                #pragma unroll
                for (int t2 = 0; t2 < 16; t2++) {
                    float hk = hr[t2];
                    accA[r] = fmaf(hk, wA[t2], accA[r]);
                    accB[r] = fmaf(hk, wB[t2], accB[r]);
                }
            }
        }
        #pragma unroll
        for (int r = 0; r < 8; r++) {
            Hd[(size_t)(rb + r) * 64 + lane] = accA[r];
            Hs[(size_t)(rb + r) * 64 + lane] = accB[r];
        }
    }
}

// ---------- edge pass 1: sum(z), sum(z^2) per column; packed CSR ----------
__global__ __launch_bounds__(256) void k_edge_stats(const float* __restrict__ Hd, const float* __restrict__ Hs,
                                                    const int* __restrict__ rowptr, const int2* __restrict__ edata,
                                                    const float* __restrict__ w1e,
                                                    float* __restrict__ esum, float* __restrict__ esq, int n) {
    __shared__ float rs[4][64], rq[4][64];
    int wid = threadIdx.x >> 6, lane = threadIdx.x & 63;
    int gw = (blockIdx.x * 256 + threadIdx.x) >> 6;
    int nw = (gridDim.x * 256) >> 6;
    float wj = w1e[lane];
    float s = 0.0f, q = 0.0f;
    for (int node = gw; node < n; node += nw) {
        int nu = rfl(node);
        int e0 = rowptr[nu], e1 = rowptr[nu + 1];
        if (e0 == e1) continue;
        float hd = Hd[(size_t)nu * 64 + lane];
        int e = e0;
        for (; e + 4 <= e1; e += 4) {
            int2 p0 = edata[e], p1 = edata[e + 1], p2 = edata[e + 2], p3 = edata[e + 3];
            float z0 = hd + Hs[(size_t)p0.x * 64 + lane] + __int_as_float(p0.y) * wj;
            float z1 = hd + Hs[(size_t)p1.x * 64 + lane] + __int_as_float(p1.y) * wj;
            float z2 = hd + Hs[(size_t)p2.x * 64 + lane] + __int_as_float(p2.y) * wj;
            float z3 = hd + Hs[(size_t)p3.x * 64 + lane] + __int_as_float(p3.y) * wj;
            s += z0 + z1 + z2 + z3;
            q = fmaf(z0, z0, q); q = fmaf(z1, z1, q); q = fmaf(z2, z2, q); q = fmaf(z3, z3, q);
        }
        for (; e < e1; e++) {
            int2 p = edata[e];
            float z = hd + Hs[(size_t)p.x * 64 + lane] + __int_as_float(p.y) * wj;
            s += z;
            q = fmaf(z, z, q);
        }
    }
    rs[wid][lane] = s; rq[wid][lane] = q;
    __syncthreads();
    if (wid == 0) {
        float ts = rs[0][lane] + rs[1][lane] + rs[2][lane] + rs[3][lane];
        float tq = rq[0][lane] + rq[1][lane] + rq[2][lane] + rq[3][lane];
        atomicAdd(&esum[lane], ts);
        atomicAdd(&esq[lane], tq);
    }
}

// ---------- edge pass 2: sacc[n] = (sum_in silu(bn(z))) / deg ----------
__global__ __launch_bounds__(256) void k_edge_agg(const float* __restrict__ Hd, const float* __restrict__ Hs,
                                                  const int* __restrict__ rowptr, const int2* __restrict__ edata,
                                                  const float* __restrict__ w1e,
                                                  const float* __restrict__ esum, const float* __restrict__ esq,
                                                  const float* __restrict__ g1, const float* __restrict__ be1,
                                                  const float* __restrict__ degf, float* __restrict__ sacc,
                                                  int n, float invE) {
    int lane = threadIdx.x & 63;
    float mean = esum[lane] * invE;
    float var = esq[lane] * invE - mean * mean;
    float inv = rsqrtf(var + 1e-5f);
    float sc = inv * g1[lane];
    float sh = fmaf(-mean, sc, be1[lane]);
    float wj = w1e[lane];
    int gw = (blockIdx.x * 256 + threadIdx.x) >> 6;
    int nw = (gridDim.x * 256) >> 6;
    for (int node = gw; node < n; node += nw) {
        int nu = rfl(node);
        int e0 = rowptr[nu], e1 = rowptr[nu + 1];
        float acc = 0.0f;
        float hd = Hd[(size_t)nu * 64 + lane];
        int e = e0;
        for (; e + 4 <= e1; e += 4) {
            int2 p0 = edata[e], p1 = edata[e + 1], p2 = edata[e + 2], p3 = edata[e + 3];
            float z0 = hd + Hs[(size_t)p0.x * 64 + lane] + __int_as_float(p0.y) * wj;
            float z1 = hd + Hs[(size_t)p1.x * 64 + lane] + __int_as_float(p1.y) * wj;
            float z2 = hd + Hs[(size_t)p2.x * 64 + lane] + __int_as_float(p2.y) * wj;
            float z3 = hd + Hs[(size_t)p3.x * 64 + lane] + __int_as_float(p3.y) * wj;
            acc += silu_f(fmaf(z0, sc, sh)) + silu_f(fmaf(z1, sc, sh))
                 + silu_f(fmaf(z2, sc, sh)) + silu_f(fmaf(z3, sc, sh));
        }
        for (; e < e1; e++) {
            int2 p = edata[e];
            float z = hd + Hs[(size_t)p.x * 64 + lane] + __int_as_float(p.y) * wj;
            acc += silu_f(fmaf(z, sc, sh));
        }
        sacc[(size_t)nu * 64 + lane] = acc / degf[nu];
    }
}

// ---------- node update: u = h@U1 + sacc@W2p + gate*b2p + ub ; stats(u) ----------
__global__ __launch_bounds__(256) void k_node_upd(const float* __restrict__ h, const float* __restrict__ sacc,
                                                  const float* __restrict__ U1, const float* __restrict__ W2p,
                                                  const float* __restrict__ b2p, const float* __restrict__ ub,
                                                  const int* __restrict__ rowptr, float* __restrict__ u,
                                                  float* __restrict__ usum, float* __restrict__ usq, int n) {
    __shared__ float sU[4096], sP[4096];
    __shared__ float rs[4][64], rq[4][64];
    for (int i = threadIdx.x; i < 4096; i += 256) { sU[i] = U1[i]; sP[i] = W2p[i]; }
    __syncthreads();
    int wid = threadIdx.x >> 6, lane = threadIdx.x & 63;
    int gw = (blockIdx.x * 256 + threadIdx.x) >> 6;
    int nw = (gridDim.x * 256) >> 6;
    float b2j = b2p[lane], ubj = ub[lane];
    float s = 0.0f, q = 0.0f;
    int tiles = n >> 3;
    for (int t = gw; t < tiles; t += nw) {
        int rb = rfl(t << 3);
        float acc[8];
        #pragma unroll
        for (int r = 0; r < 8; r++) {
            int c0 = rowptr[rb + r], c1 = rowptr[rb + r + 1];
            acc[r] = ubj + (c1 > c0 ? b2j : 0.0f);
        }
        for (int kb = 0; kb < 64; kb += 16) {
            float wU[16], wP[16];
            #pragma unroll
            for (int t2 = 0; t2 < 16; t2++) { wU[t2] = sU[(kb + t2) * 64 + lane]; wP[t2] = sP[(kb + t2) * 64 + lane]; }
            #pragma unroll
            for (int r = 0; r < 8; r++) {
                const float* hr = h + (size_t)(rb + r) * 64 + kb;
                const float* sr = sacc + (size_t)(rb + r) * 64 + kb;
                #pragma unroll
                for (int t2 = 0; t2 < 16; t2++) {
                    acc[r] = fmaf(hr[t2], wU[t2], acc[r]);
                    acc[r] = fmaf(sr[t2], wP[t2], acc[r]);
                }
            }
        }
        #pragma unroll
        for (int r = 0; r < 8; r++) {
            u[(size_t)(rb + r) * 64 + lane] = acc[r];
            s += acc[r];
            q = fmaf(acc[r], acc[r], q);
        }
    }
    rs[wid][lane] = s; rq[wid][lane] = q;
    __syncthreads();
    if (wid == 0) {
        float ts = rs[0][lane] + rs[1][lane] + rs[2][lane] + rs[3][lane];
        float tq = rq[0][lane] + rq[1][lane] + rq[2][lane] + rq[3][lane];
        atomicAdd(&usum[lane], ts);
        atomicAdd(&usq[lane], tq);
    }
}

// ---------- node BN + SiLU (layers 0..3): h = silu(u*scale + shift) ----------
__global__ __launch_bounds__(256) void k_node_bn(const float* __restrict__ u, const float* __restrict__ usum,
                                                 const float* __restrict__ usq, const float* __restrict__ g,
                                                 const float* __restrict__ be, float* __restrict__ h,
                                                 int n, float invN) {
    __shared__ float ssc[64], ssh[64];
    if (threadIdx.x < 64) {
        int j = threadIdx.x;
        float mean = usum[j] * invN;
        float var = usq[j] * invN - mean * mean;
        float inv = rsqrtf(var + 1e-5f);
        float sc = inv * g[j];
        ssc[j] = sc;
        ssh[j] = fmaf(-mean, sc, be[j]);
    }
    __syncthreads();
    int total = n * 64;
    for (int i = blockIdx.x * 256 + threadIdx.x; i < total; i += gridDim.x * 256) {
        int j = i & 63;
        float y = fmaf(u[i], ssc[j], ssh[j]);
        h[i] = silu_f(y);
    }
}

// ---------- layer-4 BN + SiLU fused with pooling ----------
__global__ __launch_bounds__(256) void k_bn_pool(const float* __restrict__ u, const float* __restrict__ usum,
                                                 const float* __restrict__ usq, const float* __restrict__ g,
                                                 const float* __restrict__ be, const int* __restrict__ batch,
                                                 float* __restrict__ gsum, float* __restrict__ gcnt,
                                                 int n, float invN) {
    __shared__ float ssc[64], ssh[64];
    if (threadIdx.x < 64) {
        int j = threadIdx.x;
        float mean = usum[j] * invN;
        float var = usq[j] * invN - mean * mean;
        float inv = rsqrtf(var + 1e-5f);
        float sc = inv * g[j];
        ssc[j] = sc;
        ssh[j] = fmaf(-mean, sc, be[j]);
    }
    __syncthreads();
    int lane = threadIdx.x & 63;
    int gw = (blockIdx.x * 256 + threadIdx.x) >> 6;
    int nw = (gridDim.x * 256) >> 6;
    int per = (n + nw - 1) / nw;
    int start = gw * per;
    int end = start + per; if (end > n) end = n;
    if (start >= end) return;
    float sc = ssc[lane], sh = ssh[lane];
    int cur = batch[start];
    float acc = 0.0f, c = 0.0f;
    for (int i = start; i < end; i++) {
        int b = batch[i];
        if (b != cur) {
            atomicAdd(&gsum[(size_t)cur * 64 + lane], acc);
            if (lane == 0) atomicAdd(&gcnt[cur], c);
            cur = b; acc = 0.0f; c = 0.0f;
        }
        float y = fmaf(u[(size_t)i * 64 + lane], sc, sh);
        acc += silu_f(y);
        c += 1.0f;
    }
    atomicAdd(&gsum[(size_t)cur * 64 + lane], acc);
    if (lane == 0) atomicAdd(&gcnt[cur], c);
}

// ---------- output: silu((gsum/cnt) @ out_W + out_b) ----------
__global__ __launch_bounds__(256) void k_out(const float* __restrict__ gsum, const float* __restrict__ gcnt,
                                             const float* __restrict__ OW, const float* __restrict__ ob,
                                             float* __restrict__ out, int G) {
    __shared__ float sW[4096];
    for (int i = threadIdx.x; i < 4096; i += 256) sW[i] = OW[i];
    __syncthreads();
    int lane = threadIdx.x & 63;
    int gw = (blockIdx.x * 256 + threadIdx.x) >> 6;
    int nw = (gridDim.x * 256) >> 6;
    for (int g = gw; g < G; g += nw) {
        int gu = rfl(g);
        float c = gcnt[gu]; if (c < 1.0f) c = 1.0f;
        float ci = 1.0f / c;
        float acc = ob[lane];
        const float* gr = gsum + (size_t)gu * 64;
        #pragma unroll
        for (int k = 0; k < 64; k++) acc = fmaf(gr[k] * ci, sW[k * 64 + lane], acc);
        out[(size_t)gu * 64 + lane] = silu_f(acc);
    }
}

extern "C" void kernel_launch(void* const* d_in, const int* in_sizes, int n_in,
                              void* d_out, int out_size, void* d_ws, size_t ws_size,
                              hipStream_t stream) {
    const int N = NN, E = EE, G = GG, L = LL;
    const float* x         = (const float*)d_in[0];
    const float* edge_attr = (const float*)d_in[1];
    const int*   edge_index= (const int*)d_in[2];
    const int*   batch     = (const int*)d_in[3];
    const float* node_W    = (const float*)d_in[4];
    const float* node_b    = (const float*)d_in[5];
    const float* msg_W1    = (const float*)d_in[6];
    const float* msg_b1    = (const float*)d_in[7];
    const float* msg_g1    = (const float*)d_in[8];
    const float* msg_be1   = (const float*)d_in[9];
    const float* msg_W2    = (const float*)d_in[10];
    const float* msg_b2    = (const float*)d_in[11];
    const float* upd_W     = (const float*)d_in[12];
    const float* upd_b     = (const float*)d_in[13];
    const float* upd_g     = (const float*)d_in[14];
    const float* upd_be    = (const float*)d_in[15];
    const float* out_W     = (const float*)d_in[16];
    const float* out_b     = (const float*)d_in[17];
    float* out = (float*)d_out;

    char* ws = (char*)d_ws;
    size_t off = 0;
    auto alloc = [&](size_t b) { size_t o = off; off = (off + b + 255) & ~(size_t)255; return o; };
    float* h    = (float*)(ws + alloc((size_t)N * 64 * 4));
    float* Hd   = (float*)(ws + alloc((size_t)N * 64 * 4));   // reused as u
    float* Hs   = (float*)(ws + alloc((size_t)N * 64 * 4));
    float* sacc = (float*)(ws + alloc((size_t)N * 64 * 4));
    int2*  edata= (int2*) (ws + alloc((size_t)E * 8));
    int* rowptr = (int*)  (ws + alloc((size_t)(N + 1) * 4));
    float* degf = (float*)(ws + alloc((size_t)N * 4));
    float* W2p  = (float*)(ws + alloc((size_t)L * 4096 * 4));
    float* b2p  = (float*)(ws + alloc((size_t)L * 64 * 4));
    // zero-init region: fill + stats + gsum/gcnt — contiguous, single memset
    size_t zero_begin = off;
    int*   fill = (int*)  (ws + alloc((size_t)N * 4));
    float* stats= (float*)(ws + alloc((size_t)L * 4 * 64 * 4));  // per layer: esum,esq,usum,usq
    float* gsum = (float*)(ws + alloc((size_t)(G * 64 + G) * 4));
    size_t zero_end = off;
    float* gcnt = gsum + (size_t)G * 64;
    float* u = Hd;

    hipMemsetAsync(ws + zero_begin, 0, zero_end - zero_begin, stream);

    // CSR build
    k_hist<<<(E + 255) / 256, 256, 0, stream>>>(edge_index, fill, E);
    k_scan<<<1, 1024, 0, stream>>>(fill, rowptr, degf, fill, N);
    k_scatter<<<(E + 255) / 256, 256, 0, stream>>>(edge_index, edge_attr, rowptr, fill, edata, E);

    // weight fold + node embedding
    k_fold<<<L, 256, 0, stream>>>(msg_W2, msg_b2, upd_W, W2p, b2p);
    k_node_emb<<<1024, 256, 0, stream>>>(x, node_W, node_b, h, N);

    for (int l = 0; l < L; l++) {
        const float* W1  = msg_W1 + (size_t)l * 129 * 64;
        const float* w1e = W1 + 128 * 64;
        float* esum = stats + (size_t)l * 256;
        float* esq  = esum + 64;
        float* usum = esum + 128;
        float* usq  = esum + 192;
        k_node_pre<<<1024, 256, 0, stream>>>(h, W1, msg_b1 + l * 64, Hd, Hs, N);
        k_edge_stats<<<2048, 256, 0, stream>>>(Hd, Hs, rowptr, edata, w1e, esum, esq, N);
        k_edge_agg<<<2048, 256, 0, stream>>>(Hd, Hs, rowptr, edata, w1e, esum, esq,
                                             msg_g1 + l * 64, msg_be1 + l * 64, degf, sacc, N, 1.0f / E);
        k_node_upd<<<1024, 256, 0, stream>>>(h, sacc, upd_W + (size_t)l * 8192, W2p + (size_t)l * 4096,
                                             b2p + (size_t)l * 64, upd_b + l * 64, rowptr,
                                             u, usum, usq, N);
        if (l < L - 1) {
            k_node_bn<<<2048, 256, 0, stream>>>(u, usum, usq, upd_g + l * 64, upd_be + l * 64, h, N, 1.0f / N);
        } else {
            k_bn_pool<<<256, 256, 0, stream>>>(u, usum, usq, upd_g + l * 64, upd_be + l * 64,
                                               batch, gsum, gcnt, N, 1.0f / N);
        }
    }

    k_out<<<64, 256, 0, stream>>>(gsum, gcnt, out_W, out_b, out, G);
}

// Round 5
// 1434.943 us; speedup vs baseline: 2.9362x; 1.1396x over previous
//
#include <hip/hip_runtime.h>
#include <hip/hip_bf16.h>

#define NN 50000
#define EE 1200000
#define GG 256
#define LL 5

// fast silu: v_mul + v_exp + v_add + v_rcp + v_mul (vs IEEE expf+div ~15 instrs)
__device__ __forceinline__ float silu_f(float x) {
    return x * __builtin_amdgcn_rcpf(1.0f + __expf(-x));
}
__device__ __forceinline__ int rfl(int x) { return __builtin_amdgcn_readfirstlane(x); }

// ---------- CSR build ----------
__global__ __launch_bounds__(256) void k_hist(const int* __restrict__ ei, int* __restrict__ fill, int E) {
    int e = blockIdx.x * 256 + threadIdx.x;
    if (e < E) atomicAdd(&fill[ei[E + e]], 1);
}

__global__ __launch_bounds__(1024) void k_scan(const int* __restrict__ cnt, int* __restrict__ rowptr,
                                               float* __restrict__ degf, int* __restrict__ fill, int n) {
    __shared__ int wsum[16];
    __shared__ int carry_s;
    int tid = threadIdx.x, lane = tid & 63, wid = tid >> 6;
    if (tid == 0) carry_s = 0;
    __syncthreads();
    for (int base = 0; base < n; base += 1024) {
        int i = base + tid;
        int v = (i < n) ? cnt[i] : 0;
        int x = v;
        #pragma unroll
        for (int off = 1; off < 64; off <<= 1) {
            int t = __shfl_up(x, off);
            if (lane >= off) x += t;
        }
        if (lane == 63) wsum[wid] = x;
        __syncthreads();
        if (wid == 0 && lane < 16) {
            int w = wsum[lane];
            #pragma unroll
            for (int off = 1; off < 16; off <<= 1) {
                int t = __shfl_up(w, off);
                if (lane >= off) w += t;
            }
            wsum[lane] = w;
        }
        __syncthreads();
        int waveoff = (wid == 0) ? 0 : wsum[wid - 1];
        int inc = x + waveoff;
        int c = carry_s;
        int chunk_total = wsum[15];
        __syncthreads();
        if (i < n) {
            rowptr[i + 1] = c + inc;
            degf[i] = (float)(v > 0 ? v : 1);
            fill[i] = 0;
        }
        if (tid == 0) {
            if (base == 0) rowptr[0] = 0;
            carry_s = c + chunk_total;
        }
        __syncthreads();
    }
}

// packed scatter: one 8B write per edge into edata = {src, ea_bits}
__global__ __launch_bounds__(256) void k_scatter(const int* __restrict__ ei, const float* __restrict__ ea,
                                                 const int* __restrict__ rowptr, int* __restrict__ fill,
                                                 int2* __restrict__ edata, int E) {
    int e = blockIdx.x * 256 + threadIdx.x;
    if (e < E) {
        int d = ei[E + e];
        int pos = atomicAdd(&fill[d], 1);
        int idx = rowptr[d] + pos;
        edata[idx] = make_int2(ei[e], __float_as_int(ea[e]));
    }
}

// ---------- weight fold: W2p[l] = msg_W2[l] @ U2[l], b2p[l] = msg_b2[l] @ U2[l] ----------
__global__ __launch_bounds__(256) void k_fold(const float* __restrict__ msg_W2, const float* __restrict__ msg_b2,
                                              const float* __restrict__ upd_W, float* __restrict__ W2p,
                                              float* __restrict__ b2p) {
    int l = blockIdx.x;
    const float* W2 = msg_W2 + (size_t)l * 4096;
    const float* U2 = upd_W + (size_t)l * 8192 + 4096;
    int lane = threadIdx.x & 63, wid = threadIdx.x >> 6;
    for (int ii = 0; ii < 16; ii++) {
        int i = rfl(wid * 16 + ii);
        float acc = 0.0f;
        for (int k = 0; k < 64; k++) acc = fmaf(W2[i * 64 + k], U2[k * 64 + lane], acc);
        W2p[(size_t)l * 4096 + i * 64 + lane] = acc;
    }
    if (wid == 0) {
        float acc = 0.0f;
        for (int k = 0; k < 64; k++) acc = fmaf(msg_b2[l * 64 + k], U2[k * 64 + lane], acc);
        b2p[l * 64 + lane] = acc;
    }
}

// ---------- node embedding: h = x @ node_W + node_b ----------
__global__ __launch_bounds__(256) void k_node_emb(const float* __restrict__ x, const float* __restrict__ W,
                                                  const float* __restrict__ b, float* __restrict__ h, int n) {
    __shared__ float sW[92 * 64];
    for (int i = threadIdx.x; i < 92 * 64; i += 256) sW[i] = W[i];
    __syncthreads();
    int lane = threadIdx.x & 63;
    int gw = (blockIdx.x * 256 + threadIdx.x) >> 6;
    int nw = (gridDim.x * 256) >> 6;
    float bj = b[lane];
    int tiles = n >> 3;
    for (int t = gw; t < tiles; t += nw) {
        int rb = rfl(t << 3);
        float acc[8];
        #pragma unroll
        for (int r = 0; r < 8; r++) acc[r] = bj;
        for (int kb = 0; kb < 80; kb += 16) {
            float wv[16];
            #pragma unroll
            for (int t2 = 0; t2 < 16; t2++) wv[t2] = sW[(kb + t2) * 64 + lane];
            #pragma unroll
            for (int r = 0; r < 8; r++) {
                const float* xr = x + (size_t)(rb + r) * 92 + kb;
                #pragma unroll
                for (int t2 = 0; t2 < 16; t2++) acc[r] = fmaf(xr[t2], wv[t2], acc[r]);
            }
        }
        {
            float wv[12];
            #pragma unroll
            for (int t2 = 0; t2 < 12; t2++) wv[t2] = sW[(80 + t2) * 64 + lane];
            #pragma unroll
            for (int r = 0; r < 8; r++) {
                const float* xr = x + (size_t)(rb + r) * 92 + 80;
                #pragma unroll
                for (int t2 = 0; t2 < 12; t2++) acc[r] = fmaf(xr[t2], wv[t2], acc[r]);
            }
        }
        #pragma unroll
        for (int r = 0; r < 8; r++) h[(size_t)(rb + r) * 64 + lane] = acc[r];
    }
}

// ---------- per-layer: Hd = h@W1[0:64] + b1 ; Hs = h@W1[64:128] (both fp32) ----------
__global__ __launch_bounds__(256) void k_node_pre(const float* __restrict__ h, const float* __restrict__ W1,
                                                  const float* __restrict__ b1, float* __restrict__ Hd,
                                                  float* __restrict__ Hs, int n) {
    __shared__ float sA[4096], sB[4096];
    for (int i = threadIdx.x; i < 4096; i += 256) { sA[i] = W1[i]; sB[i] = W1[4096 + i]; }
    __syncthreads();
    int lane = threadIdx.x & 63;
    int gw = (blockIdx.x * 256 + threadIdx.x) >> 6;
    int nw = (gridDim.x * 256) >> 6;
    float bj = b1[lane];
    int tiles = n >> 3;
    for (int t = gw; t < tiles; t += nw) {
        int rb = rfl(t << 3);
        float accA[8], accB[8];
        #pragma unroll
        for (int r = 0; r < 8; r++) { accA[r] = bj; accB[r] = 0.0f; }
        for (int kb = 0; kb < 64; kb += 16) {
            float wA[16], wB[16];
            #pragma unroll
            for (int t2 = 0; t2 < 16; t2++) { wA[t2] = sA[(kb + t2) * 64 + lane]; wB[t2] = sB[(kb + t2) * 64 + lane]; }
            #pragma unroll
            for (int r = 0; r < 8; r++) {
                const float* hr = h + (size_t)(rb + r) * 64 + kb;
                #pragma unroll
                for (int t2 = 0; t2 < 16; t2++) {
                    float hk = hr[t2];
                    accA[r] = fmaf(hk, wA[t2], accA[r]);
                    accB[r] = fmaf(hk, wB[t2], accB[r]);
                }
            }
        }
        #pragma unroll
        for (int r = 0; r < 8; r++) {
            Hd[(size_t)(rb + r) * 64 + lane] = accA[r];
            Hs[(size_t)(rb + r) * 64 + lane] = accB[r];
        }
    }
}

// ---------- edge pass 1: sum(z), sum(z^2); scalarized CSR loads, unroll 8 ----------
__global__ __launch_bounds__(256) void k_edge_stats(const float* __restrict__ Hd, const float* __restrict__ Hs,
                                                    const int* __restrict__ rowptr, const int2* __restrict__ edata,
                                                    const float* __restrict__ w1e,
                                                    float* __restrict__ esum, float* __restrict__ esq, int n) {
    __shared__ float rs[4][64], rq[4][64];
    int wid = threadIdx.x >> 6, lane = threadIdx.x & 63;
    int gw = (blockIdx.x * 256 + threadIdx.x) >> 6;
    int nw = (gridDim.x * 256) >> 6;
    float wj = w1e[lane];
    float s = 0.0f, q = 0.0f;
    for (int node = gw; node < n; node += nw) {
        int nu = rfl(node);
        int e0 = rowptr[nu], e1 = rowptr[nu + 1];
        if (e0 == e1) continue;
        float hd = Hd[(size_t)nu * 64 + lane];
        int e = e0;
        for (; e + 8 <= e1; e += 8) {
            float hs[8], av[8];
            #pragma unroll
            for (int j = 0; j < 8; j++) {
                int2 p = edata[e + j];
                int sidx = rfl(p.x);
                av[j] = __int_as_float(rfl(p.y));
                hs[j] = Hs[(size_t)sidx * 64 + lane];
            }
            #pragma unroll
            for (int j = 0; j < 8; j++) {
                float z = fmaf(av[j], wj, hd) + hs[j];
                s += z;
                q = fmaf(z, z, q);
            }
        }
        for (; e < e1; e++) {
            int2 p = edata[e];
            int sidx = rfl(p.x);
            float a = __int_as_float(rfl(p.y));
            float z = fmaf(a, wj, hd) + Hs[(size_t)sidx * 64 + lane];
            s += z;
            q = fmaf(z, z, q);
        }
    }
    rs[wid][lane] = s; rq[wid][lane] = q;
    __syncthreads();
    if (wid == 0) {
        float ts = rs[0][lane] + rs[1][lane] + rs[2][lane] + rs[3][lane];
        float tq = rq[0][lane] + rq[1][lane] + rq[2][lane] + rq[3][lane];
        atomicAdd(&esum[lane], ts);
        atomicAdd(&esq[lane], tq);
    }
}

// ---------- edge pass 2: sacc[n] = (sum_in silu(bn(z))) / deg; scalarized, unroll 8, fast silu ----------
__global__ __launch_bounds__(256) void k_edge_agg(const float* __restrict__ Hd, const float* __restrict__ Hs,
                                                  const int* __restrict__ rowptr, const int2* __restrict__ edata,
                                                  const float* __restrict__ w1e,
                                                  const float* __restrict__ esum, const float* __restrict__ esq,
                                                  const float* __restrict__ g1, const float* __restrict__ be1,
                                                  const float* __restrict__ degf, float* __restrict__ sacc,
                                                  int n, float invE) {
    int lane = threadIdx.x & 63;
    float mean = esum[lane] * invE;
    float var = esq[lane] * invE - mean * mean;
    float inv = rsqrtf(var + 1e-5f);
    float sc = inv * g1[lane];
    float sh = fmaf(-mean, sc, be1[lane]);
    float wj = w1e[lane];
    int gw = (blockIdx.x * 256 + threadIdx.x) >> 6;
    int nw = (gridDim.x * 256) >> 6;
    for (int node = gw; node < n; node += nw) {
        int nu = rfl(node);
        int e0 = rowptr[nu], e1 = rowptr[nu + 1];
        float acc = 0.0f;
        float hd = Hd[(size_t)nu * 64 + lane];
        int e = e0;
        for (; e + 8 <= e1; e += 8) {
            float hs[8], av[8];
            #pragma unroll
            for (int j = 0; j < 8; j++) {
                int2 p = edata[e + j];
                int sidx = rfl(p.x);
                av[j] = __int_as_float(rfl(p.y));
                hs[j] = Hs[(size_t)sidx * 64 + lane];
            }
            #pragma unroll
            for (int j = 0; j < 8; j++) {
                float z = fmaf(av[j], wj, hd) + hs[j];
                acc += silu_f(fmaf(z, sc, sh));
            }
        }
        for (; e < e1; e++) {
            int2 p = edata[e];
            int sidx = rfl(p.x);
            float a = __int_as_float(rfl(p.y));
            float z = fmaf(a, wj, hd) + Hs[(size_t)sidx * 64 + lane];
            acc += silu_f(fmaf(z, sc, sh));
        }
        sacc[(size_t)nu * 64 + lane] = acc / degf[nu];
    }
}

// ---------- node update: u = h@U1 + sacc@W2p + gate*b2p + ub ; stats(u) ----------
__global__ __launch_bounds__(256) void k_node_upd(const float* __restrict__ h, const float* __restrict__ sacc,
                                                  const float* __restrict__ U1, const float* __restrict__ W2p,
                                                  const float* __restrict__ b2p, const float* __restrict__ ub,
                                                  const int* __restrict__ rowptr, float* __restrict__ u,
                                                  float* __restrict__ usum, float* __restrict__ usq, int n) {
    __shared__ float sU[4096], sP[4096];
    __shared__ float rs[4][64], rq[4][64];
    for (int i = threadIdx.x; i < 4096; i += 256) { sU[i] = U1[i]; sP[i] = W2p[i]; }
    __syncthreads();
    int wid = threadIdx.x >> 6, lane = threadIdx.x & 63;
    int gw = (blockIdx.x * 256 + threadIdx.x) >> 6;
    int nw = (gridDim.x * 256) >> 6;
    float b2j = b2p[lane], ubj = ub[lane];
    float s = 0.0f, q = 0.0f;
    int tiles = n >> 3;
    for (int t = gw; t < tiles; t += nw) {
        int rb = rfl(t << 3);
        float acc[8];
        #pragma unroll
        for (int r = 0; r < 8; r++) {
            int c0 = rowptr[rb + r], c1 = rowptr[rb + r + 1];
            acc[r] = ubj + (c1 > c0 ? b2j : 0.0f);
        }
        for (int kb = 0; kb < 64; kb += 16) {
            float wU[16], wP[16];
            #pragma unroll
            for (int t2 = 0; t2 < 16; t2++) { wU[t2] = sU[(kb + t2) * 64 + lane]; wP[t2] = sP[(kb + t2) * 64 + lane]; }
            #pragma unroll
            for (int r = 0; r < 8; r++) {
                const float* hr = h + (size_t)(rb + r) * 64 + kb;
                const float* sr = sacc + (size_t)(rb + r) * 64 + kb;
                #pragma unroll
                for (int t2 = 0; t2 < 16; t2++) {
                    acc[r] = fmaf(hr[t2], wU[t2], acc[r]);
                    acc[r] = fmaf(sr[t2], wP[t2], acc[r]);
                }
            }
        }
        #pragma unroll
        for (int r = 0; r < 8; r++) {
            u[(size_t)(rb + r) * 64 + lane] = acc[r];
            s += acc[r];
            q = fmaf(acc[r], acc[r], q);
        }
    }
    rs[wid][lane] = s; rq[wid][lane] = q;
    __syncthreads();
    if (wid == 0) {
        float ts = rs[0][lane] + rs[1][lane] + rs[2][lane] + rs[3][lane];
        float tq = rq[0][lane] + rq[1][lane] + rq[2][lane] + rq[3][lane];
        atomicAdd(&usum[lane], ts);
        atomicAdd(&usq[lane], tq);
    }
}

// ---------- node BN + SiLU (layers 0..3): h = silu(u*scale + shift) ----------
__global__ __launch_bounds__(256) void k_node_bn(const float* __restrict__ u, const float* __restrict__ usum,
                                                 const float* __restrict__ usq, const float* __restrict__ g,
                                                 const float* __restrict__ be, float* __restrict__ h,
                                                 int n, float invN) {
    __shared__ float ssc[64], ssh[64];
    if (threadIdx.x < 64) {
        int j = threadIdx.x;
        float mean = usum[j] * invN;
        float var = usq[j] * invN - mean * mean;
        float inv = rsqrtf(var + 1e-5f);
        float sc = inv * g[j];
        ssc[j] = sc;
        ssh[j] = fmaf(-mean, sc, be[j]);
    }
    __syncthreads();
    int total = n * 64;
    for (int i = blockIdx.x * 256 + threadIdx.x; i < total; i += gridDim.x * 256) {
        int j = i & 63;
        float y = fmaf(u[i], ssc[j], ssh[j]);
        h[i] = silu_f(y);
    }
}

// ---------- layer-4 BN + SiLU fused with pooling ----------
__global__ __launch_bounds__(256) void k_bn_pool(const float* __restrict__ u, const float* __restrict__ usum,
                                                 const float* __restrict__ usq, const float* __restrict__ g,
                                                 const float* __restrict__ be, const int* __restrict__ batch,
                                                 float* __restrict__ gsum, float* __restrict__ gcnt,
                                                 int n, float invN) {
    __shared__ float ssc[64], ssh[64];
    if (threadIdx.x < 64) {
        int j = threadIdx.x;
        float mean = usum[j] * invN;
        float var = usq[j] * invN - mean * mean;
        float inv = rsqrtf(var + 1e-5f);
        float sc = inv * g[j];
        ssc[j] = sc;
        ssh[j] = fmaf(-mean, sc, be[j]);
    }
    __syncthreads();
    int lane = threadIdx.x & 63;
    int gw = (blockIdx.x * 256 + threadIdx.x) >> 6;
    int nw = (gridDim.x * 256) >> 6;
    int per = (n + nw - 1) / nw;
    int start = gw * per;
    int end = start + per; if (end > n) end = n;
    if (start >= end) return;
    float sc = ssc[lane], sh = ssh[lane];
    int cur = batch[start];
    float acc = 0.0f, c = 0.0f;
    for (int i = start; i < end; i++) {
        int b = batch[i];
        if (b != cur) {
            atomicAdd(&gsum[(size_t)cur * 64 + lane], acc);
            if (lane == 0) atomicAdd(&gcnt[cur], c);
            cur = b; acc = 0.0f; c = 0.0f;
        }
        float y = fmaf(u[(size_t)i * 64 + lane], sc, sh);
        acc += silu_f(y);
        c += 1.0f;
    }
    atomicAdd(&gsum[(size_t)cur * 64 + lane], acc);
    if (lane == 0) atomicAdd(&gcnt[cur], c);
}

// ---------- output: silu((gsum/cnt) @ out_W + out_b) ----------
__global__ __launch_bounds__(256) void k_out(const float* __restrict__ gsum, const float* __restrict__ gcnt,
                                             const float* __restrict__ OW, const float* __restrict__ ob,
                                             float* __restrict__ out, int G) {
    __shared__ float sW[4096];
    for (int i = threadIdx.x; i < 4096; i += 256) sW[i] = OW[i];
    __syncthreads();
    int lane = threadIdx.x & 63;
    int gw = (blockIdx.x * 256 + threadIdx.x) >> 6;
    int nw = (gridDim.x * 256) >> 6;
    for (int g = gw; g < G; g += nw) {
        int gu = rfl(g);
        float c = gcnt[gu]; if (c < 1.0f) c = 1.0f;
        float ci = 1.0f / c;
        float acc = ob[lane];
        const float* gr = gsum + (size_t)gu * 64;
        #pragma unroll
        for (int k = 0; k < 64; k++) acc = fmaf(gr[k] * ci, sW[k * 64 + lane], acc);
        out[(size_t)gu * 64 + lane] = silu_f(acc);
    }
}

extern "C" void kernel_launch(void* const* d_in, const int* in_sizes, int n_in,
                              void* d_out, int out_size, void* d_ws, size_t ws_size,
                              hipStream_t stream) {
    const int N = NN, E = EE, G = GG, L = LL;
    const float* x         = (const float*)d_in[0];
    const float* edge_attr = (const float*)d_in[1];
    const int*   edge_index= (const int*)d_in[2];
    const int*   batch     = (const int*)d_in[3];
    const float* node_W    = (const float*)d_in[4];
    const float* node_b    = (const float*)d_in[5];
    const float* msg_W1    = (const float*)d_in[6];
    const float* msg_b1    = (const float*)d_in[7];
    const float* msg_g1    = (const float*)d_in[8];
    const float* msg_be1   = (const float*)d_in[9];
    const float* msg_W2    = (const float*)d_in[10];
    const float* msg_b2    = (const float*)d_in[11];
    const float* upd_W     = (const float*)d_in[12];
    const float* upd_b     = (const float*)d_in[13];
    const float* upd_g     = (const float*)d_in[14];
    const float* upd_be    = (const float*)d_in[15];
    const float* out_W     = (const float*)d_in[16];
    const float* out_b     = (const float*)d_in[17];
    float* out = (float*)d_out;

    char* ws = (char*)d_ws;
    size_t off = 0;
    auto alloc = [&](size_t b) { size_t o = off; off = (off + b + 255) & ~(size_t)255; return o; };
    float* h    = (float*)(ws + alloc((size_t)N * 64 * 4));
    float* Hd   = (float*)(ws + alloc((size_t)N * 64 * 4));   // reused as u
    float* Hs   = (float*)(ws + alloc((size_t)N * 64 * 4));
    float* sacc = (float*)(ws + alloc((size_t)N * 64 * 4));
    int2*  edata= (int2*) (ws + alloc((size_t)E * 8));
    int* rowptr = (int*)  (ws + alloc((size_t)(N + 1) * 4));
    float* degf = (float*)(ws + alloc((size_t)N * 4));
    float* W2p  = (float*)(ws + alloc((size_t)L * 4096 * 4));
    float* b2p  = (float*)(ws + alloc((size_t)L * 64 * 4));
    // zero-init region: fill + stats + gsum/gcnt — contiguous, single memset
    size_t zero_begin = off;
    int*   fill = (int*)  (ws + alloc((size_t)N * 4));
    float* stats= (float*)(ws + alloc((size_t)L * 4 * 64 * 4));  // per layer: esum,esq,usum,usq
    float* gsum = (float*)(ws + alloc((size_t)(G * 64 + G) * 4));
    size_t zero_end = off;
    float* gcnt = gsum + (size_t)G * 64;
    float* u = Hd;

    hipMemsetAsync(ws + zero_begin, 0, zero_end - zero_begin, stream);

    // CSR build
    k_hist<<<(E + 255) / 256, 256, 0, stream>>>(edge_index, fill, E);
    k_scan<<<1, 1024, 0, stream>>>(fill, rowptr, degf, fill, N);
    k_scatter<<<(E + 255) / 256, 256, 0, stream>>>(edge_index, edge_attr, rowptr, fill, edata, E);

    // weight fold + node embedding
    k_fold<<<L, 256, 0, stream>>>(msg_W2, msg_b2, upd_W, W2p, b2p);
    k_node_emb<<<1024, 256, 0, stream>>>(x, node_W, node_b, h, N);

    for (int l = 0; l < L; l++) {
        const float* W1  = msg_W1 + (size_t)l * 129 * 64;
        const float* w1e = W1 + 128 * 64;
        float* esum = stats + (size_t)l * 256;
        float* esq  = esum + 64;
        float* usum = esum + 128;
        float* usq  = esum + 192;
        k_node_pre<<<1024, 256, 0, stream>>>(h, W1, msg_b1 + l * 64, Hd, Hs, N);
        k_edge_stats<<<2048, 256, 0, stream>>>(Hd, Hs, rowptr, edata, w1e, esum, esq, N);
        k_edge_agg<<<2048, 256, 0, stream>>>(Hd, Hs, rowptr, edata, w1e, esum, esq,
                                             msg_g1 + l * 64, msg_be1 + l * 64, degf, sacc, N, 1.0f / E);
        k_node_upd<<<1024, 256, 0, stream>>>(h, sacc, upd_W + (size_t)l * 8192, W2p + (size_t)l * 4096,
                                             b2p + (size_t)l * 64, upd_b + l * 64, rowptr,
                                             u, usum, usq, N);
        if (l < L - 1) {
            k_node_bn<<<2048, 256, 0, stream>>>(u, usum, usq, upd_g + l * 64, upd_be + l * 64, h, N, 1.0f / N);
        } else {
            k_bn_pool<<<256, 256, 0, stream>>>(u, usum, usq, upd_g + l * 64, upd_be + l * 64,
                                               batch, gsum, gcnt, N, 1.0f / N);
        }
    }

    k_out<<<64, 256, 0, stream>>>(gsum, gcnt, out_W, out_b, out, G);
}

// Round 6
// 1431.106 us; speedup vs baseline: 2.9441x; 1.0027x over previous
//
#include <hip/hip_runtime.h>
#include <hip/hip_bf16.h>

#define NN 50000
#define EE 1200000
#define GG 256
#define LL 5

// fast silu: v_mul + v_exp + v_add + v_rcp + v_mul
__device__ __forceinline__ float silu_f(float x) {
    return x * __builtin_amdgcn_rcpf(1.0f + __expf(-x));
}
__device__ __forceinline__ int rfl(int x) { return __builtin_amdgcn_readfirstlane(x); }

// ---------- CSR build ----------
__global__ __launch_bounds__(256) void k_hist(const int* __restrict__ ei, int* __restrict__ fill, int E) {
    int e = blockIdx.x * 256 + threadIdx.x;
    if (e < E) atomicAdd(&fill[ei[E + e]], 1);
}

__global__ __launch_bounds__(1024) void k_scan(const int* __restrict__ cnt, int* __restrict__ rowptr,
                                               float* __restrict__ degf, int* __restrict__ fill, int n) {
    __shared__ int wsum[16];
    __shared__ int carry_s;
    int tid = threadIdx.x, lane = tid & 63, wid = tid >> 6;
    if (tid == 0) carry_s = 0;
    __syncthreads();
    for (int base = 0; base < n; base += 1024) {
        int i = base + tid;
        int v = (i < n) ? cnt[i] : 0;
        int x = v;
        #pragma unroll
        for (int off = 1; off < 64; off <<= 1) {
            int t = __shfl_up(x, off);
            if (lane >= off) x += t;
        }
        if (lane == 63) wsum[wid] = x;
        __syncthreads();
        if (wid == 0 && lane < 16) {
            int w = wsum[lane];
            #pragma unroll
            for (int off = 1; off < 16; off <<= 1) {
                int t = __shfl_up(w, off);
                if (lane >= off) w += t;
            }
            wsum[lane] = w;
        }
        __syncthreads();
        int waveoff = (wid == 0) ? 0 : wsum[wid - 1];
        int inc = x + waveoff;
        int c = carry_s;
        int chunk_total = wsum[15];
        __syncthreads();
        if (i < n) {
            rowptr[i + 1] = c + inc;
            degf[i] = (float)(v > 0 ? v : 1);
            fill[i] = 0;
        }
        if (tid == 0) {
            if (base == 0) rowptr[0] = 0;
            carry_s = c + chunk_total;
        }
        __syncthreads();
    }
}

// packed scatter: one 8B write per edge into edata = {src, ea_bits}
__global__ __launch_bounds__(256) void k_scatter(const int* __restrict__ ei, const float* __restrict__ ea,
                                                 const int* __restrict__ rowptr, int* __restrict__ fill,
                                                 int2* __restrict__ edata, int E) {
    int e = blockIdx.x * 256 + threadIdx.x;
    if (e < E) {
        int d = ei[E + e];
        int pos = atomicAdd(&fill[d], 1);
        int idx = rowptr[d] + pos;
        edata[idx] = make_int2(ei[e], __float_as_int(ea[e]));
    }
}

// ---------- weight fold ----------
__global__ __launch_bounds__(256) void k_fold(const float* __restrict__ msg_W2, const float* __restrict__ msg_b2,
                                              const float* __restrict__ upd_W, float* __restrict__ W2p,
                                              float* __restrict__ b2p) {
    int l = blockIdx.x;
    const float* W2 = msg_W2 + (size_t)l * 4096;
    const float* U2 = upd_W + (size_t)l * 8192 + 4096;
    int lane = threadIdx.x & 63, wid = threadIdx.x >> 6;
    for (int ii = 0; ii < 16; ii++) {
        int i = rfl(wid * 16 + ii);
        float acc = 0.0f;
        for (int k = 0; k < 64; k++) acc = fmaf(W2[i * 64 + k], U2[k * 64 + lane], acc);
        W2p[(size_t)l * 4096 + i * 64 + lane] = acc;
    }
    if (wid == 0) {
        float acc = 0.0f;
        for (int k = 0; k < 64; k++) acc = fmaf(msg_b2[l * 64 + k], U2[k * 64 + lane], acc);
        b2p[l * 64 + lane] = acc;
    }
}

// ---------- node embedding ----------
__global__ __launch_bounds__(256) void k_node_emb(const float* __restrict__ x, const float* __restrict__ W,
                                                  const float* __restrict__ b, float* __restrict__ h, int n) {
    __shared__ float sW[92 * 64];
    for (int i = threadIdx.x; i < 92 * 64; i += 256) sW[i] = W[i];
    __syncthreads();
    int lane = threadIdx.x & 63;
    int gw = (blockIdx.x * 256 + threadIdx.x) >> 6;
    int nw = (gridDim.x * 256) >> 6;
    float bj = b[lane];
    int tiles = n >> 3;
    for (int t = gw; t < tiles; t += nw) {
        int rb = rfl(t << 3);
        float acc[8];
        #pragma unroll
        for (int r = 0; r < 8; r++) acc[r] = bj;
        for (int kb = 0; kb < 80; kb += 16) {
            float wv[16];
            #pragma unroll
            for (int t2 = 0; t2 < 16; t2++) wv[t2] = sW[(kb + t2) * 64 + lane];
            #pragma unroll
            for (int r = 0; r < 8; r++) {
                const float* xr = x + (size_t)(rb + r) * 92 + kb;
                #pragma unroll
                for (int t2 = 0; t2 < 16; t2++) acc[r] = fmaf(xr[t2], wv[t2], acc[r]);
            }
        }
        {
            float wv[12];
            #pragma unroll
            for (int t2 = 0; t2 < 12; t2++) wv[t2] = sW[(80 + t2) * 64 + lane];
            #pragma unroll
            for (int r = 0; r < 8; r++) {
                const float* xr = x + (size_t)(rb + r) * 92 + 80;
                #pragma unroll
                for (int t2 = 0; t2 < 12; t2++) acc[r] = fmaf(xr[t2], wv[t2], acc[r]);
            }
        }
        #pragma unroll
        for (int r = 0; r < 8; r++) h[(size_t)(rb + r) * 64 + lane] = acc[r];
    }
}

// ---------- per-layer: Hd = h@W1[0:64] + b1 ; Hs = h@W1[64:128] ----------
__global__ __launch_bounds__(256) void k_node_pre(const float* __restrict__ h, const float* __restrict__ W1,
                                                  const float* __restrict__ b1, float* __restrict__ Hd,
                                                  float* __restrict__ Hs, int n) {
    __shared__ float sA[4096], sB[4096];
    for (int i = threadIdx.x; i < 4096; i += 256) { sA[i] = W1[i]; sB[i] = W1[4096 + i]; }
    __syncthreads();
    int lane = threadIdx.x & 63;
    int gw = (blockIdx.x * 256 + threadIdx.x) >> 6;
    int nw = (gridDim.x * 256) >> 6;
    float bj = b1[lane];
    int tiles = n >> 3;
    for (int t = gw; t < tiles; t += nw) {
        int rb = rfl(t << 3);
        float accA[8], accB[8];
        #pragma unroll
        for (int r = 0; r < 8; r++) { accA[r] = bj; accB[r] = 0.0f; }
        for (int kb = 0; kb < 64; kb += 16) {
            float wA[16], wB[16];
            #pragma unroll
            for (int t2 = 0; t2 < 16; t2++) { wA[t2] = sA[(kb + t2) * 64 + lane]; wB[t2] = sB[(kb + t2) * 64 + lane]; }
            #pragma unroll
            for (int r = 0; r < 8; r++) {
                const float* hr = h + (size_t)(rb + r) * 64 + kb;
                #pragma unroll
                for (int t2 = 0; t2 < 16; t2++) {
                    float hk = hr[t2];
                    accA[r] = fmaf(hk, wA[t2], accA[r]);
                    accB[r] = fmaf(hk, wB[t2], accB[r]);
                }
            }
        }
        #pragma unroll
        for (int r = 0; r < 8; r++) {
            Hd[(size_t)(rb + r) * 64 + lane] = accA[r];
            Hs[(size_t)(rb + r) * 64 + lane] = accB[r];
        }
    }
}

// ---------- edge pass 1: sum(z), sum(z^2); software-pipelined edata prefetch ----------
__global__ __launch_bounds__(256) void k_edge_stats(const float* __restrict__ Hd, const float* __restrict__ Hs,
                                                    const int* __restrict__ rowptr, const int2* __restrict__ edata,
                                                    const float* __restrict__ w1e,
                                                    float* __restrict__ esum, float* __restrict__ esq, int n) {
    __shared__ float rs[4][64], rq[4][64];
    int wid = threadIdx.x >> 6, lane = threadIdx.x & 63;
    int gw = (blockIdx.x * 256 + threadIdx.x) >> 6;
    int nw = (gridDim.x * 256) >> 6;
    float wj = w1e[lane];
    float s = 0.0f, q = 0.0f;
    for (int node = gw; node < n; node += nw) {
        int nu = rfl(node);
        int e0 = rowptr[nu], e1 = rowptr[nu + 1];
        int m = e1 - e0;
        if (m <= 0) continue;
        float hd = Hd[(size_t)nu * 64 + lane];
        int e = e0;
        int nb = m >> 3;
        if (nb > 0) {
            int2 ed[8];
            #pragma unroll
            for (int j = 0; j < 8; j++) ed[j] = edata[e0 + j];
            for (int b = 0; b < nb; b++) {
                float hs[8], av[8];
                #pragma unroll
                for (int j = 0; j < 8; j++) {
                    int sidx = rfl(ed[j].x);
                    av[j] = __int_as_float(rfl(ed[j].y));
                    hs[j] = Hs[(size_t)sidx * 64 + lane];
                }
                int eb = e + 8;
                if (b + 1 < nb) {   // prefetch next batch while gathers are in flight
                    #pragma unroll
                    for (int j = 0; j < 8; j++) ed[j] = edata[eb + j];
                }
                #pragma unroll
                for (int j = 0; j < 8; j++) {
                    float z = fmaf(av[j], wj, hd) + hs[j];
                    s += z;
                    q = fmaf(z, z, q);
                }
                e = eb;
            }
        }
        for (; e < e1; e++) {
            int2 p = edata[e];
            int sidx = rfl(p.x);
            float a = __int_as_float(rfl(p.y));
            float z = fmaf(a, wj, hd) + Hs[(size_t)sidx * 64 + lane];
            s += z;
            q = fmaf(z, z, q);
        }
    }
    rs[wid][lane] = s; rq[wid][lane] = q;
    __syncthreads();
    if (wid == 0) {
        float ts = rs[0][lane] + rs[1][lane] + rs[2][lane] + rs[3][lane];
        float tq = rq[0][lane] + rq[1][lane] + rq[2][lane] + rq[3][lane];
        atomicAdd(&esum[lane], ts);
        atomicAdd(&esq[lane], tq);
    }
}

// ---------- edge pass 2: sacc = (sum_in silu(bn(z)))/deg; pipelined ----------
__global__ __launch_bounds__(256) void k_edge_agg(const float* __restrict__ Hd, const float* __restrict__ Hs,
                                                  const int* __restrict__ rowptr, const int2* __restrict__ edata,
                                                  const float* __restrict__ w1e,
                                                  const float* __restrict__ esum, const float* __restrict__ esq,
                                                  const float* __restrict__ g1, const float* __restrict__ be1,
                                                  const float* __restrict__ degf, float* __restrict__ sacc,
                                                  int n, float invE) {
    int lane = threadIdx.x & 63;
    float mean = esum[lane] * invE;
    float var = esq[lane] * invE - mean * mean;
    float inv = rsqrtf(var + 1e-5f);
    float sc = inv * g1[lane];
    float sh = fmaf(-mean, sc, be1[lane]);
    float wj = w1e[lane];
    int gw = (blockIdx.x * 256 + threadIdx.x) >> 6;
    int nw = (gridDim.x * 256) >> 6;
    for (int node = gw; node < n; node += nw) {
        int nu = rfl(node);
        int e0 = rowptr[nu], e1 = rowptr[nu + 1];
        int m = e1 - e0;
        float acc = 0.0f;
        float hd = Hd[(size_t)nu * 64 + lane];
        int e = e0;
        int nb = m >> 3;
        if (nb > 0) {
            int2 ed[8];
            #pragma unroll
            for (int j = 0; j < 8; j++) ed[j] = edata[e0 + j];
            for (int b = 0; b < nb; b++) {
                float hs[8], av[8];
                #pragma unroll
                for (int j = 0; j < 8; j++) {
                    int sidx = rfl(ed[j].x);
                    av[j] = __int_as_float(rfl(ed[j].y));
                    hs[j] = Hs[(size_t)sidx * 64 + lane];
                }
                int eb = e + 8;
                if (b + 1 < nb) {
                    #pragma unroll
                    for (int j = 0; j < 8; j++) ed[j] = edata[eb + j];
                }
                #pragma unroll
                for (int j = 0; j < 8; j++) {
                    float z = fmaf(av[j], wj, hd) + hs[j];
                    acc += silu_f(fmaf(z, sc, sh));
                }
                e = eb;
            }
        }
        for (; e < e1; e++) {
            int2 p = edata[e];
            int sidx = rfl(p.x);
            float a = __int_as_float(rfl(p.y));
            float z = fmaf(a, wj, hd) + Hs[(size_t)sidx * 64 + lane];
            acc += silu_f(fmaf(z, sc, sh));
        }
        sacc[(size_t)nu * 64 + lane] = acc / degf[nu];
    }
}

// ---------- node update: u = h@U1 + sacc@W2p + gate*b2p + ub ; stats(u) ----------
__global__ __launch_bounds__(256) void k_node_upd(const float* __restrict__ h, const float* __restrict__ sacc,
                                                  const float* __restrict__ U1, const float* __restrict__ W2p,
                                                  const float* __restrict__ b2p, const float* __restrict__ ub,
                                                  const int* __restrict__ rowptr, float* __restrict__ u,
                                                  float* __restrict__ usum, float* __restrict__ usq, int n) {
    __shared__ float sU[4096], sP[4096];
    __shared__ float rs[4][64], rq[4][64];
    for (int i = threadIdx.x; i < 4096; i += 256) { sU[i] = U1[i]; sP[i] = W2p[i]; }
    __syncthreads();
    int wid = threadIdx.x >> 6, lane = threadIdx.x & 63;
    int gw = (blockIdx.x * 256 + threadIdx.x) >> 6;
    int nw = (gridDim.x * 256) >> 6;
    float b2j = b2p[lane], ubj = ub[lane];
    float s = 0.0f, q = 0.0f;
    int tiles = n >> 3;
    for (int t = gw; t < tiles; t += nw) {
        int rb = rfl(t << 3);
        float acc[8];
        #pragma unroll
        for (int r = 0; r < 8; r++) {
            int c0 = rowptr[rb + r], c1 = rowptr[rb + r + 1];
            acc[r] = ubj + (c1 > c0 ? b2j : 0.0f);
        }
        for (int kb = 0; kb < 64; kb += 16) {
            float wU[16], wP[16];
            #pragma unroll
            for (int t2 = 0; t2 < 16; t2++) { wU[t2] = sU[(kb + t2) * 64 + lane]; wP[t2] = sP[(kb + t2) * 64 + lane]; }
            #pragma unroll
            for (int r = 0; r < 8; r++) {
                const float* hr = h + (size_t)(rb + r) * 64 + kb;
                const float* sr = sacc + (size_t)(rb + r) * 64 + kb;
                #pragma unroll
                for (int t2 = 0; t2 < 16; t2++) {
                    acc[r] = fmaf(hr[t2], wU[t2], acc[r]);
                    acc[r] = fmaf(sr[t2], wP[t2], acc[r]);
                }
            }
        }
        #pragma unroll
        for (int r = 0; r < 8; r++) {
            u[(size_t)(rb + r) * 64 + lane] = acc[r];
            s += acc[r];
            q = fmaf(acc[r], acc[r], q);
        }
    }
    rs[wid][lane] = s; rq[wid][lane] = q;
    __syncthreads();
    if (wid == 0) {
        float ts = rs[0][lane] + rs[1][lane] + rs[2][lane] + rs[3][lane];
        float tq = rq[0][lane] + rq[1][lane] + rq[2][lane] + rq[3][lane];
        atomicAdd(&usum[lane], ts);
        atomicAdd(&usq[lane], tq);
    }
}

// ---------- node BN + SiLU (layers 0..3) ----------
__global__ __launch_bounds__(256) void k_node_bn(const float* __restrict__ u, const float* __restrict__ usum,
                                                 const float* __restrict__ usq, const float* __restrict__ g,
                                                 const float* __restrict__ be, float* __restrict__ h,
                                                 int n, float invN) {
    __shared__ float ssc[64], ssh[64];
    if (threadIdx.x < 64) {
        int j = threadIdx.x;
        float mean = usum[j] * invN;
        float var = usq[j] * invN - mean * mean;
        float inv = rsqrtf(var + 1e-5f);
        float sc = inv * g[j];
        ssc[j] = sc;
        ssh[j] = fmaf(-mean, sc, be[j]);
    }
    __syncthreads();
    int total = n * 64;
    for (int i = blockIdx.x * 256 + threadIdx.x; i < total; i += gridDim.x * 256) {
        int j = i & 63;
        float y = fmaf(u[i], ssc[j], ssh[j]);
        h[i] = silu_f(y);
    }
}

// ---------- layer-4 BN + SiLU fused with pooling ----------
__global__ __launch_bounds__(256) void k_bn_pool(const float* __restrict__ u, const float* __restrict__ usum,
                                                 const float* __restrict__ usq, const float* __restrict__ g,
                                                 const float* __restrict__ be, const int* __restrict__ batch,
                                                 float* __restrict__ gsum, float* __restrict__ gcnt,
                                                 int n, float invN) {
    __shared__ float ssc[64], ssh[64];
    if (threadIdx.x < 64) {
        int j = threadIdx.x;
        float mean = usum[j] * invN;
        float var = usq[j] * invN - mean * mean;
        float inv = rsqrtf(var + 1e-5f);
        float sc = inv * g[j];
        ssc[j] = sc;
        ssh[j] = fmaf(-mean, sc, be[j]);
    }
    __syncthreads();
    int lane = threadIdx.x & 63;
    int gw = (blockIdx.x * 256 + threadIdx.x) >> 6;
    int nw = (gridDim.x * 256) >> 6;
    int per = (n + nw - 1) / nw;
    int start = gw * per;
    int end = start + per; if (end > n) end = n;
    if (start >= end) return;
    float sc = ssc[lane], sh = ssh[lane];
    int cur = batch[start];
    float acc = 0.0f, c = 0.0f;
    for (int i = start; i < end; i++) {
        int b = batch[i];
        if (b != cur) {
            atomicAdd(&gsum[(size_t)cur * 64 + lane], acc);
            if (lane == 0) atomicAdd(&gcnt[cur], c);
            cur = b; acc = 0.0f; c = 0.0f;
        }
        float y = fmaf(u[(size_t)i * 64 + lane], sc, sh);
        acc += silu_f(y);
        c += 1.0f;
    }
    atomicAdd(&gsum[(size_t)cur * 64 + lane], acc);
    if (lane == 0) atomicAdd(&gcnt[cur], c);
}

// ---------- output ----------
__global__ __launch_bounds__(256) void k_out(const float* __restrict__ gsum, const float* __restrict__ gcnt,
                                             const float* __restrict__ OW, const float* __restrict__ ob,
                                             float* __restrict__ out, int G) {
    __shared__ float sW[4096];
    for (int i = threadIdx.x; i < 4096; i += 256) sW[i] = OW[i];
    __syncthreads();
    int lane = threadIdx.x & 63;
    int gw = (blockIdx.x * 256 + threadIdx.x) >> 6;
    int nw = (gridDim.x * 256) >> 6;
    for (int g = gw; g < G; g += nw) {
        int gu = rfl(g);
        float c = gcnt[gu]; if (c < 1.0f) c = 1.0f;
        float ci = 1.0f / c;
        float acc = ob[lane];
        const float* gr = gsum + (size_t)gu * 64;
        #pragma unroll
        for (int k = 0; k < 64; k++) acc = fmaf(gr[k] * ci, sW[k * 64 + lane], acc);
        out[(size_t)gu * 64 + lane] = silu_f(acc);
    }
}

extern "C" void kernel_launch(void* const* d_in, const int* in_sizes, int n_in,
                              void* d_out, int out_size, void* d_ws, size_t ws_size,
                              hipStream_t stream) {
    const int N = NN, E = EE, G = GG, L = LL;
    const float* x         = (const float*)d_in[0];
    const float* edge_attr = (const float*)d_in[1];
    const int*   edge_index= (const int*)d_in[2];
    const int*   batch     = (const int*)d_in[3];
    const float* node_W    = (const float*)d_in[4];
    const float* node_b    = (const float*)d_in[5];
    const float* msg_W1    = (const float*)d_in[6];
    const float* msg_b1    = (const float*)d_in[7];
    const float* msg_g1    = (const float*)d_in[8];
    const float* msg_be1   = (const float*)d_in[9];
    const float* msg_W2    = (const float*)d_in[10];
    const float* msg_b2    = (const float*)d_in[11];
    const float* upd_W     = (const float*)d_in[12];
    const float* upd_b     = (const float*)d_in[13];
    const float* upd_g     = (const float*)d_in[14];
    const float* upd_be    = (const float*)d_in[15];
    const float* out_W     = (const float*)d_in[16];
    const float* out_b     = (const float*)d_in[17];
    float* out = (float*)d_out;

    char* ws = (char*)d_ws;
    size_t off = 0;
    auto alloc = [&](size_t b) { size_t o = off; off = (off + b + 255) & ~(size_t)255; return o; };
    float* h    = (float*)(ws + alloc((size_t)N * 64 * 4));
    float* Hd   = (float*)(ws + alloc((size_t)N * 64 * 4));   // reused as u
    float* Hs   = (float*)(ws + alloc((size_t)N * 64 * 4));
    float* sacc = (float*)(ws + alloc((size_t)N * 64 * 4));
    int2*  edata= (int2*) (ws + alloc((size_t)E * 8));
    int* rowptr = (int*)  (ws + alloc((size_t)(N + 1) * 4));
    float* degf = (float*)(ws + alloc((size_t)N * 4));
    float* W2p  = (float*)(ws + alloc((size_t)L * 4096 * 4));
    float* b2p  = (float*)(ws + alloc((size_t)L * 64 * 4));
    size_t zero_begin = off;
    int*   fill = (int*)  (ws + alloc((size_t)N * 4));
    float* stats= (float*)(ws + alloc((size_t)L * 4 * 64 * 4));
    float* gsum = (float*)(ws + alloc((size_t)(G * 64 + G) * 4));
    size_t zero_end = off;
    float* gcnt = gsum + (size_t)G * 64;
    float* u = Hd;

    hipMemsetAsync(ws + zero_begin, 0, zero_end - zero_begin, stream);

    // CSR build
    k_hist<<<(E + 255) / 256, 256, 0, stream>>>(edge_index, fill, E);
    k_scan<<<1, 1024, 0, stream>>>(fill, rowptr, degf, fill, N);
    k_scatter<<<(E + 255) / 256, 256, 0, stream>>>(edge_index, edge_attr, rowptr, fill, edata, E);

    // weight fold + node embedding
    k_fold<<<L, 256, 0, stream>>>(msg_W2, msg_b2, upd_W, W2p, b2p);
    k_node_emb<<<1024, 256, 0, stream>>>(x, node_W, node_b, h, N);

    for (int l = 0; l < L; l++) {
        const float* W1  = msg_W1 + (size_t)l * 129 * 64;
        const float* w1e = W1 + 128 * 64;
        float* esum = stats + (size_t)l * 256;
        float* esq  = esum + 64;
        float* usum = esum + 128;
        float* usq  = esum + 192;
        k_node_pre<<<1024, 256, 0, stream>>>(h, W1, msg_b1 + l * 64, Hd, Hs, N);
        k_edge_stats<<<2048, 256, 0, stream>>>(Hd, Hs, rowptr, edata, w1e, esum, esq, N);
        k_edge_agg<<<2048, 256, 0, stream>>>(Hd, Hs, rowptr, edata, w1e, esum, esq,
                                             msg_g1 + l * 64, msg_be1 + l * 64, degf, sacc, N, 1.0f / E);
        k_node_upd<<<1024, 256, 0, stream>>>(h, sacc, upd_W + (size_t)l * 8192, W2p + (size_t)l * 4096,
                                             b2p + (size_t)l * 64, upd_b + l * 64, rowptr,
                                             u, usum, usq, N);
        if (l < L - 1) {
            k_node_bn<<<2048, 256, 0, stream>>>(u, usum, usq, upd_g + l * 64, upd_be + l * 64, h, N, 1.0f / N);
        } else {
            k_bn_pool<<<256, 256, 0, stream>>>(u, usum, usq, upd_g + l * 64, upd_be + l * 64,
                                               batch, gsum, gcnt, N, 1.0f / N);
        }
    }

    k_out<<<64, 256, 0, stream>>>(gsum, gcnt, out_W, out_b, out, G);
}

// Round 7
// 1358.995 us; speedup vs baseline: 3.1003x; 1.0531x over previous
//
#include <hip/hip_runtime.h>
#include <hip/hip_bf16.h>

#define NN 50000
#define EE 1200000
#define GG 256
#define LL 5

// fast silu
__device__ __forceinline__ float silu_f(float x) {
    return x * __builtin_amdgcn_rcpf(1.0f + __expf(-x));
}
__device__ __forceinline__ int rfl(int x) { return __builtin_amdgcn_readfirstlane(x); }

// ---------- CSR build ----------
__global__ __launch_bounds__(256) void k_hist(const int* __restrict__ ei, int* __restrict__ fill, int E) {
    int e = blockIdx.x * 256 + threadIdx.x;
    if (e < E) atomicAdd(&fill[ei[E + e]], 1);
}

__global__ __launch_bounds__(1024) void k_scan(const int* __restrict__ cnt, int* __restrict__ rowptr,
                                               float* __restrict__ degf, int* __restrict__ fill, int n) {
    __shared__ int wsum[16];
    __shared__ int carry_s;
    int tid = threadIdx.x, lane = tid & 63, wid = tid >> 6;
    if (tid == 0) carry_s = 0;
    __syncthreads();
    for (int base = 0; base < n; base += 1024) {
        int i = base + tid;
        int v = (i < n) ? cnt[i] : 0;
        int x = v;
        #pragma unroll
        for (int off = 1; off < 64; off <<= 1) {
            int t = __shfl_up(x, off);
            if (lane >= off) x += t;
        }
        if (lane == 63) wsum[wid] = x;
        __syncthreads();
        if (wid == 0 && lane < 16) {
            int w = wsum[lane];
            #pragma unroll
            for (int off = 1; off < 16; off <<= 1) {
                int t = __shfl_up(w, off);
                if (lane >= off) w += t;
            }
            wsum[lane] = w;
        }
        __syncthreads();
        int waveoff = (wid == 0) ? 0 : wsum[wid - 1];
        int inc = x + waveoff;
        int c = carry_s;
        int chunk_total = wsum[15];
        __syncthreads();
        if (i < n) {
            rowptr[i + 1] = c + inc;
            degf[i] = (float)(v > 0 ? v : 1);
            fill[i] = 0;
        }
        if (tid == 0) {
            if (base == 0) rowptr[0] = 0;
            carry_s = c + chunk_total;
        }
        __syncthreads();
    }
}

// packed scatter: ONE 4B write per edge. v = (ea15 << 17) | src  (src < 2^17, ea in [0,1) -> 15-bit fixed)
__global__ __launch_bounds__(256) void k_scatter(const int* __restrict__ ei, const float* __restrict__ ea,
                                                 const int* __restrict__ rowptr, int* __restrict__ fill,
                                                 unsigned int* __restrict__ edata, int E) {
    int e = blockIdx.x * 256 + threadIdx.x;
    if (e < E) {
        int d = ei[E + e];
        int pos = atomicAdd(&fill[d], 1);
        int idx = rowptr[d] + pos;
        int ea15 = (int)(ea[e] * 32768.0f + 0.5f);
        if (ea15 > 32767) ea15 = 32767;
        edata[idx] = ((unsigned int)ea15 << 17) | (unsigned int)ei[e];
    }
}

// ---------- weight fold ----------
__global__ __launch_bounds__(256) void k_fold(const float* __restrict__ msg_W2, const float* __restrict__ msg_b2,
                                              const float* __restrict__ upd_W, float* __restrict__ W2p,
                                              float* __restrict__ b2p) {
    int l = blockIdx.x;
    const float* W2 = msg_W2 + (size_t)l * 4096;
    const float* U2 = upd_W + (size_t)l * 8192 + 4096;
    int lane = threadIdx.x & 63, wid = threadIdx.x >> 6;
    for (int ii = 0; ii < 16; ii++) {
        int i = rfl(wid * 16 + ii);
        float acc = 0.0f;
        for (int k = 0; k < 64; k++) acc = fmaf(W2[i * 64 + k], U2[k * 64 + lane], acc);
        W2p[(size_t)l * 4096 + i * 64 + lane] = acc;
    }
    if (wid == 0) {
        float acc = 0.0f;
        for (int k = 0; k < 64; k++) acc = fmaf(msg_b2[l * 64 + k], U2[k * 64 + lane], acc);
        b2p[l * 64 + lane] = acc;
    }
}

// ---------- node embedding ----------
__global__ __launch_bounds__(256) void k_node_emb(const float* __restrict__ x, const float* __restrict__ W,
                                                  const float* __restrict__ b, float* __restrict__ h, int n) {
    __shared__ float sW[92 * 64];
    for (int i = threadIdx.x; i < 92 * 64; i += 256) sW[i] = W[i];
    __syncthreads();
    int lane = threadIdx.x & 63;
    int gw = (blockIdx.x * 256 + threadIdx.x) >> 6;
    int nw = (gridDim.x * 256) >> 6;
    float bj = b[lane];
    int tiles = n >> 3;
    for (int t = gw; t < tiles; t += nw) {
        int rb = rfl(t << 3);
        float acc[8];
        #pragma unroll
        for (int r = 0; r < 8; r++) acc[r] = bj;
        for (int kb = 0; kb < 80; kb += 16) {
            float wv[16];
            #pragma unroll
            for (int t2 = 0; t2 < 16; t2++) wv[t2] = sW[(kb + t2) * 64 + lane];
            #pragma unroll
            for (int r = 0; r < 8; r++) {
                const float* xr = x + (size_t)(rb + r) * 92 + kb;
                #pragma unroll
                for (int t2 = 0; t2 < 16; t2++) acc[r] = fmaf(xr[t2], wv[t2], acc[r]);
            }
        }
        {
            float wv[12];
            #pragma unroll
            for (int t2 = 0; t2 < 12; t2++) wv[t2] = sW[(80 + t2) * 64 + lane];
            #pragma unroll
            for (int r = 0; r < 8; r++) {
                const float* xr = x + (size_t)(rb + r) * 92 + 80;
                #pragma unroll
                for (int t2 = 0; t2 < 12; t2++) acc[r] = fmaf(xr[t2], wv[t2], acc[r]);
            }
        }
        #pragma unroll
        for (int r = 0; r < 8; r++) h[(size_t)(rb + r) * 64 + lane] = acc[r];
    }
}

// ---------- per-layer: Hd = h@W1[0:64] + b1 (fp32) ; Hs = h@W1[64:128] (fp16) ----------
__global__ __launch_bounds__(256) void k_node_pre(const float* __restrict__ h, const float* __restrict__ W1,
                                                  const float* __restrict__ b1, float* __restrict__ Hd,
                                                  _Float16* __restrict__ Hs, int n) {
    __shared__ float sA[4096], sB[4096];
    for (int i = threadIdx.x; i < 4096; i += 256) { sA[i] = W1[i]; sB[i] = W1[4096 + i]; }
    __syncthreads();
    int lane = threadIdx.x & 63;
    int gw = (blockIdx.x * 256 + threadIdx.x) >> 6;
    int nw = (gridDim.x * 256) >> 6;
    float bj = b1[lane];
    int tiles = n >> 3;
    for (int t = gw; t < tiles; t += nw) {
        int rb = rfl(t << 3);
        float accA[8], accB[8];
        #pragma unroll
        for (int r = 0; r < 8; r++) { accA[r] = bj; accB[r] = 0.0f; }
        for (int kb = 0; kb < 64; kb += 16) {
            float wA[16], wB[16];
            #pragma unroll
            for (int t2 = 0; t2 < 16; t2++) { wA[t2] = sA[(kb + t2) * 64 + lane]; wB[t2] = sB[(kb + t2) * 64 + lane]; }
            #pragma unroll
            for (int r = 0; r < 8; r++) {
                const float* hr = h + (size_t)(rb + r) * 64 + kb;
                #pragma unroll
                for (int t2 = 0; t2 < 16; t2++) {
                    float hk = hr[t2];
                    accA[r] = fmaf(hk, wA[t2], accA[r]);
                    accB[r] = fmaf(hk, wB[t2], accB[r]);
                }
            }
        }
        #pragma unroll
        for (int r = 0; r < 8; r++) {
            Hd[(size_t)(rb + r) * 64 + lane] = accA[r];
            Hs[(size_t)(rb + r) * 64 + lane] = (_Float16)accB[r];
        }
    }
}

// ---------- edge pass 1: sum(z), sum(z^2); fp16 gathers, 4B packed edata ----------
__global__ __launch_bounds__(256) void k_edge_stats(const float* __restrict__ Hd, const _Float16* __restrict__ Hs,
                                                    const int* __restrict__ rowptr, const unsigned int* __restrict__ edata,
                                                    const float* __restrict__ w1e,
                                                    float* __restrict__ esum, float* __restrict__ esq, int n) {
    __shared__ float rs[4][64], rq[4][64];
    int wid = threadIdx.x >> 6, lane = threadIdx.x & 63;
    int gw = (blockIdx.x * 256 + threadIdx.x) >> 6;
    int nw = (gridDim.x * 256) >> 6;
    float wj = w1e[lane] * (1.0f / 32768.0f);
    float s = 0.0f, q = 0.0f;
    for (int node = gw; node < n; node += nw) {
        int nu = rfl(node);
        int e0 = rowptr[nu], e1 = rowptr[nu + 1];
        if (e0 == e1) continue;
        float hd = Hd[(size_t)nu * 64 + lane];
        int e = e0;
        for (; e + 8 <= e1; e += 8) {
            float hs[8], av[8];
            #pragma unroll
            for (int j = 0; j < 8; j++) {
                unsigned int p = edata[e + j];
                int sidx = rfl((int)(p & 0x1FFFFu));
                av[j] = (float)rfl((int)(p >> 17));
                hs[j] = (float)Hs[(size_t)sidx * 64 + lane];
            }
            #pragma unroll
            for (int j = 0; j < 8; j++) {
                float z = fmaf(av[j], wj, hd) + hs[j];
                s += z;
                q = fmaf(z, z, q);
            }
        }
        for (; e < e1; e++) {
            unsigned int p = edata[e];
            int sidx = rfl((int)(p & 0x1FFFFu));
            float a = (float)rfl((int)(p >> 17));
            float z = fmaf(a, wj, hd) + (float)Hs[(size_t)sidx * 64 + lane];
            s += z;
            q = fmaf(z, z, q);
        }
    }
    rs[wid][lane] = s; rq[wid][lane] = q;
    __syncthreads();
    if (wid == 0) {
        float ts = rs[0][lane] + rs[1][lane] + rs[2][lane] + rs[3][lane];
        float tq = rq[0][lane] + rq[1][lane] + rq[2][lane] + rq[3][lane];
        atomicAdd(&esum[lane], ts);
        atomicAdd(&esq[lane], tq);
    }
}

// ---------- edge pass 2: sacc = (sum_in silu(bn(z)))/deg; fp16 gathers ----------
__global__ __launch_bounds__(256) void k_edge_agg(const float* __restrict__ Hd, const _Float16* __restrict__ Hs,
                                                  const int* __restrict__ rowptr, const unsigned int* __restrict__ edata,
                                                  const float* __restrict__ w1e,
                                                  const float* __restrict__ esum, const float* __restrict__ esq,
                                                  const float* __restrict__ g1, const float* __restrict__ be1,
                                                  const float* __restrict__ degf, float* __restrict__ sacc,
                                                  int n, float invE) {
    int lane = threadIdx.x & 63;
    float mean = esum[lane] * invE;
    float var = esq[lane] * invE - mean * mean;
    float inv = rsqrtf(var + 1e-5f);
    float sc = inv * g1[lane];
    float sh = fmaf(-mean, sc, be1[lane]);
    float wj = w1e[lane] * (1.0f / 32768.0f);
    int gw = (blockIdx.x * 256 + threadIdx.x) >> 6;
    int nw = (gridDim.x * 256) >> 6;
    for (int node = gw; node < n; node += nw) {
        int nu = rfl(node);
        int e0 = rowptr[nu], e1 = rowptr[nu + 1];
        float acc = 0.0f;
        float hd = Hd[(size_t)nu * 64 + lane];
        int e = e0;
        for (; e + 8 <= e1; e += 8) {
            float hs[8], av[8];
            #pragma unroll
            for (int j = 0; j < 8; j++) {
                unsigned int p = edata[e + j];
                int sidx = rfl((int)(p & 0x1FFFFu));
                av[j] = (float)rfl((int)(p >> 17));
                hs[j] = (float)Hs[(size_t)sidx * 64 + lane];
            }
            #pragma unroll
            for (int j = 0; j < 8; j++) {
                float z = fmaf(av[j], wj, hd) + hs[j];
                acc += silu_f(fmaf(z, sc, sh));
            }
        }
        for (; e < e1; e++) {
            unsigned int p = edata[e];
            int sidx = rfl((int)(p & 0x1FFFFu));
            float a = (float)rfl((int)(p >> 17));
            float z = fmaf(a, wj, hd) + (float)Hs[(size_t)sidx * 64 + lane];
            acc += silu_f(fmaf(z, sc, sh));
        }
        sacc[(size_t)nu * 64 + lane] = acc / degf[nu];
    }
}

// ---------- node update: u = h@U1 + sacc@W2p + gate*b2p + ub ; stats(u) ----------
__global__ __launch_bounds__(256) void k_node_upd(const float* __restrict__ h, const float* __restrict__ sacc,
                                                  const float* __restrict__ U1, const float* __restrict__ W2p,
                                                  const float* __restrict__ b2p, const float* __restrict__ ub,
                                                  const int* __restrict__ rowptr, float* __restrict__ u,
                                                  float* __restrict__ usum, float* __restrict__ usq, int n) {
    __shared__ float sU[4096], sP[4096];
    __shared__ float rs[4][64], rq[4][64];
    for (int i = threadIdx.x; i < 4096; i += 256) { sU[i] = U1[i]; sP[i] = W2p[i]; }
    __syncthreads();
    int wid = threadIdx.x >> 6, lane = threadIdx.x & 63;
    int gw = (blockIdx.x * 256 + threadIdx.x) >> 6;
    int nw = (gridDim.x * 256) >> 6;
    float b2j = b2p[lane], ubj = ub[lane];
    float s = 0.0f, q = 0.0f;
    int tiles = n >> 3;
    for (int t = gw; t < tiles; t += nw) {
        int rb = rfl(t << 3);
        float acc[8];
        #pragma unroll
        for (int r = 0; r < 8; r++) {
            int c0 = rowptr[rb + r], c1 = rowptr[rb + r + 1];
            acc[r] = ubj + (c1 > c0 ? b2j : 0.0f);
        }
        for (int kb = 0; kb < 64; kb += 16) {
            float wU[16], wP[16];
            #pragma unroll
            for (int t2 = 0; t2 < 16; t2++) { wU[t2] = sU[(kb + t2) * 64 + lane]; wP[t2] = sP[(kb + t2) * 64 + lane]; }
            #pragma unroll
            for (int r = 0; r < 8; r++) {
                const float* hr = h + (size_t)(rb + r) * 64 + kb;
                const float* sr = sacc + (size_t)(rb + r) * 64 + kb;
                #pragma unroll
                for (int t2 = 0; t2 < 16; t2++) {
                    acc[r] = fmaf(hr[t2], wU[t2], acc[r]);
                    acc[r] = fmaf(sr[t2], wP[t2], acc[r]);
                }
            }
        }
        #pragma unroll
        for (int r = 0; r < 8; r++) {
            u[(size_t)(rb + r) * 64 + lane] = acc[r];
            s += acc[r];
            q = fmaf(acc[r], acc[r], q);
        }
    }
    rs[wid][lane] = s; rq[wid][lane] = q;
    __syncthreads();
    if (wid == 0) {
        float ts = rs[0][lane] + rs[1][lane] + rs[2][lane] + rs[3][lane];
        float tq = rq[0][lane] + rq[1][lane] + rq[2][lane] + rq[3][lane];
        atomicAdd(&usum[lane], ts);
        atomicAdd(&usq[lane], tq);
    }
}

// ---------- node BN + SiLU (layers 0..3) ----------
__global__ __launch_bounds__(256) void k_node_bn(const float* __restrict__ u, const float* __restrict__ usum,
                                                 const float* __restrict__ usq, const float* __restrict__ g,
                                                 const float* __restrict__ be, float* __restrict__ h,
                                                 int n, float invN) {
    __shared__ float ssc[64], ssh[64];
    if (threadIdx.x < 64) {
        int j = threadIdx.x;
        float mean = usum[j] * invN;
        float var = usq[j] * invN - mean * mean;
        float inv = rsqrtf(var + 1e-5f);
        float sc = inv * g[j];
        ssc[j] = sc;
        ssh[j] = fmaf(-mean, sc, be[j]);
    }
    __syncthreads();
    int total = n * 64;
    for (int i = blockIdx.x * 256 + threadIdx.x; i < total; i += gridDim.x * 256) {
        int j = i & 63;
        float y = fmaf(u[i], ssc[j], ssh[j]);
        h[i] = silu_f(y);
    }
}

// ---------- layer-4 BN + SiLU fused with pooling ----------
__global__ __launch_bounds__(256) void k_bn_pool(const float* __restrict__ u, const float* __restrict__ usum,
                                                 const float* __restrict__ usq, const float* __restrict__ g,
                                                 const float* __restrict__ be, const int* __restrict__ batch,
                                                 float* __restrict__ gsum, float* __restrict__ gcnt,
                                                 int n, float invN) {
    __shared__ float ssc[64], ssh[64];
    if (threadIdx.x < 64) {
        int j = threadIdx.x;
        float mean = usum[j] * invN;
        float var = usq[j] * invN - mean * mean;
        float inv = rsqrtf(var + 1e-5f);
        float sc = inv * g[j];
        ssc[j] = sc;
        ssh[j] = fmaf(-mean, sc, be[j]);
    }
    __syncthreads();
    int lane = threadIdx.x & 63;
    int gw = (blockIdx.x * 256 + threadIdx.x) >> 6;
    int nw = (gridDim.x * 256) >> 6;
    int per = (n + nw - 1) / nw;
    int start = gw * per;
    int end = start + per; if (end > n) end = n;
    if (start >= end) return;
    float sc = ssc[lane], sh = ssh[lane];
    int cur = batch[start];
    float acc = 0.0f, c = 0.0f;
    for (int i = start; i < end; i++) {
        int b = batch[i];
        if (b != cur) {
            atomicAdd(&gsum[(size_t)cur * 64 + lane], acc);
            if (lane == 0) atomicAdd(&gcnt[cur], c);
            cur = b; acc = 0.0f; c = 0.0f;
        }
        float y = fmaf(u[(size_t)i * 64 + lane], sc, sh);
        acc += silu_f(y);
        c += 1.0f;
    }
    atomicAdd(&gsum[(size_t)cur * 64 + lane], acc);
    if (lane == 0) atomicAdd(&gcnt[cur], c);
}

// ---------- output ----------
__global__ __launch_bounds__(256) void k_out(const float* __restrict__ gsum, const float* __restrict__ gcnt,
                                             const float* __restrict__ OW, const float* __restrict__ ob,
                                             float* __restrict__ out, int G) {
    __shared__ float sW[4096];
    for (int i = threadIdx.x; i < 4096; i += 256) sW[i] = OW[i];
    __syncthreads();
    int lane = threadIdx.x & 63;
    int gw = (blockIdx.x * 256 + threadIdx.x) >> 6;
    int nw = (gridDim.x * 256) >> 6;
    for (int g = gw; g < G; g += nw) {
        int gu = rfl(g);
        float c = gcnt[gu]; if (c < 1.0f) c = 1.0f;
        float ci = 1.0f / c;
        float acc = ob[lane];
        const float* gr = gsum + (size_t)gu * 64;
        #pragma unroll
        for (int k = 0; k < 64; k++) acc = fmaf(gr[k] * ci, sW[k * 64 + lane], acc);
        out[(size_t)gu * 64 + lane] = silu_f(acc);
    }
}

extern "C" void kernel_launch(void* const* d_in, const int* in_sizes, int n_in,
                              void* d_out, int out_size, void* d_ws, size_t ws_size,
                              hipStream_t stream) {
    const int N = NN, E = EE, G = GG, L = LL;
    const float* x         = (const float*)d_in[0];
    const float* edge_attr = (const float*)d_in[1];
    const int*   edge_index= (const int*)d_in[2];
    const int*   batch     = (const int*)d_in[3];
    const float* node_W    = (const float*)d_in[4];
    const float* node_b    = (const float*)d_in[5];
    const float* msg_W1    = (const float*)d_in[6];
    const float* msg_b1    = (const float*)d_in[7];
    const float* msg_g1    = (const float*)d_in[8];
    const float* msg_be1   = (const float*)d_in[9];
    const float* msg_W2    = (const float*)d_in[10];
    const float* msg_b2    = (const float*)d_in[11];
    const float* upd_W     = (const float*)d_in[12];
    const float* upd_b     = (const float*)d_in[13];
    const float* upd_g     = (const float*)d_in[14];
    const float* upd_be    = (const float*)d_in[15];
    const float* out_W     = (const float*)d_in[16];
    const float* out_b     = (const float*)d_in[17];
    float* out = (float*)d_out;

    char* ws = (char*)d_ws;
    size_t off = 0;
    auto alloc = [&](size_t b) { size_t o = off; off = (off + b + 255) & ~(size_t)255; return o; };
    float* h    = (float*)(ws + alloc((size_t)N * 64 * 4));
    float* Hd   = (float*)(ws + alloc((size_t)N * 64 * 4));   // reused as u
    _Float16* Hs = (_Float16*)(ws + alloc((size_t)N * 64 * 2));
    float* sacc = (float*)(ws + alloc((size_t)N * 64 * 4));
    unsigned int* edata = (unsigned int*)(ws + alloc((size_t)E * 4));
    int* rowptr = (int*)  (ws + alloc((size_t)(N + 1) * 4));
    float* degf = (float*)(ws + alloc((size_t)N * 4));
    float* W2p  = (float*)(ws + alloc((size_t)L * 4096 * 4));
    float* b2p  = (float*)(ws + alloc((size_t)L * 64 * 4));
    size_t zero_begin = off;
    int*   fill = (int*)  (ws + alloc((size_t)N * 4));
    float* stats= (float*)(ws + alloc((size_t)L * 4 * 64 * 4));
    float* gsum = (float*)(ws + alloc((size_t)(G * 64 + G) * 4));
    size_t zero_end = off;
    float* gcnt = gsum + (size_t)G * 64;
    float* u = Hd;

    hipMemsetAsync(ws + zero_begin, 0, zero_end - zero_begin, stream);

    // CSR build
    k_hist<<<(E + 255) / 256, 256, 0, stream>>>(edge_index, fill, E);
    k_scan<<<1, 1024, 0, stream>>>(fill, rowptr, degf, fill, N);
    k_scatter<<<(E + 255) / 256, 256, 0, stream>>>(edge_index, edge_attr, rowptr, fill, edata, E);

    // weight fold + node embedding
    k_fold<<<L, 256, 0, stream>>>(msg_W2, msg_b2, upd_W, W2p, b2p);
    k_node_emb<<<1024, 256, 0, stream>>>(x, node_W, node_b, h, N);

    for (int l = 0; l < L; l++) {
        const float* W1  = msg_W1 + (size_t)l * 129 * 64;
        const float* w1e = W1 + 128 * 64;
        float* esum = stats + (size_t)l * 256;
        float* esq  = esum + 64;
        float* usum = esum + 128;
        float* usq  = esum + 192;
        k_node_pre<<<1024, 256, 0, stream>>>(h, W1, msg_b1 + l * 64, Hd, Hs, N);
        k_edge_stats<<<2048, 256, 0, stream>>>(Hd, Hs, rowptr, edata, w1e, esum, esq, N);
        k_edge_agg<<<2048, 256, 0, stream>>>(Hd, Hs, rowptr, edata, w1e, esum, esq,
                                             msg_g1 + l * 64, msg_be1 + l * 64, degf, sacc, N, 1.0f / E);
        k_node_upd<<<1024, 256, 0, stream>>>(h, sacc, upd_W + (size_t)l * 8192, W2p + (size_t)l * 4096,
                                             b2p + (size_t)l * 64, upd_b + l * 64, rowptr,
                                             u, usum, usq, N);
        if (l < L - 1) {
            k_node_bn<<<2048, 256, 0, stream>>>(u, usum, usq, upd_g + l * 64, upd_be + l * 64, h, N, 1.0f / N);
        } else {
            k_bn_pool<<<256, 256, 0, stream>>>(u, usum, usq, upd_g + l * 64, upd_be + l * 64,
                                               batch, gsum, gcnt, N, 1.0f / N);
        }
    }

    k_out<<<64, 256, 0, stream>>>(gsum, gcnt, out_W, out_b, out, G);
}